// Round 2
// baseline (3883.383 us; speedup 1.0000x reference)
//
#include <hip/hip_runtime.h>
#include <math.h>

// Problem constants: B=32, L=4096, CH=1, H=256, NL=4, N2=32
// ws layout (float units):
//   Hb fp32 (B,H,L)            @ 0          : 33,554,432 floats (128 MiB)
//   wT fp32 (NL,256,512)       @ 33,554,432 :    524,288 floats (2 MiB)
//   y1 fp32 (B*H)              @ 34,078,720 :      8,192 floats
//   Gb bf16 (NB,H,L) chunk     @ 34,086,912 : NB*1,048,576 ushorts
// Full-G (NB=32) high-water mark: 34,086,912*4 + 33,554,432*2 = 203,456,512 B (~194 MiB)
#define WS_WT_OFF 33554432
#define WS_Y1_OFF 34078720
#define WS_GB_OFF 34086912

typedef unsigned short ushort_t;
struct us4 { ushort_t x, y, z, w; };

__device__ __forceinline__ float bf2f(ushort_t u) {
    union { unsigned int i; float f; } c; c.i = ((unsigned int)u) << 16; return c.f;
}
__device__ __forceinline__ ushort_t f2bf(float f) {
    union { float f; unsigned int i; } c; c.f = f;
    unsigned int x = c.i;
    unsigned int r = (x + 0x7FFF + ((x >> 16) & 1)) >> 16;   // RNE
    return (ushort_t)r;
}

// ---------------- encoder: h[b,h,l] = x[b,l]*enc_w[h] + enc_b[h] ----------------
__global__ __launch_bounds__(256) void enc_kernel(const float* __restrict__ x,
    const float* __restrict__ ew, const float* __restrict__ eb, float* __restrict__ Hb)
{
    int i = blockIdx.x * 256 + threadIdx.x;      // float4 units, 8,388,608 total
    int l4 = i & 1023;
    int h  = (i >> 10) & 255;
    int b  = i >> 18;
    float4 xv = *(const float4*)(x + (b << 12) + (l4 << 2));
    float w = ew[h], bb = eb[h];
    float4 o;
    o.x = fmaf(xv.x, w, bb); o.y = fmaf(xv.y, w, bb);
    o.z = fmaf(xv.z, w, bb); o.w = fmaf(xv.w, w, bb);
    *(float4*)(Hb + ((size_t)i << 2)) = o;
}

// ---------------- weight transpose: wT[li][hh][o] = glu_w[li][o][hh] ----------------
__global__ __launch_bounds__(256) void wt_kernel(const float* __restrict__ gw, float* __restrict__ wT)
{
    int i = blockIdx.x * 256 + threadIdx.x;      // 524,288
    int li = i >> 17; int rem = i & 131071;
    int hh = rem >> 9; int o = rem & 511;
    wT[i] = gw[li * 131072 + o * 256 + hh];
}

// ---------------- S4D: chunked-scan conv + D skip + exact GELU, bf16 out ----------------
// Each 32-lane group = one (b,h) row; lane = one 128-long chunk of L.
__global__ __launch_bounds__(256, 2) void s4d_kernel(
    const float* __restrict__ U, ushort_t* __restrict__ G,
    const float* __restrict__ log_dt, const float* __restrict__ log_A_real,
    const float* __restrict__ A_imag, const float* __restrict__ C_re,
    const float* __restrict__ C_im, const float* __restrict__ Dp, int li, int bh0)
{
    int t = threadIdx.x;
    int grp = t >> 5;
    int c = t & 31;                               // chunk index within row
    int bhl = blockIdx.x * 8 + grp;               // local row within this G chunk
    int bh = bh0 + bhl;                           // global row into Hb
    int hh = bh & 255;
    int pbase = (li * 256 + hh) * 32;

    float dt = expf(log_dt[li * 256 + hh]);
    float ar[32], ai[32];
    #pragma unroll
    for (int n = 0; n < 32; n++) {
        float Are = -expf(log_A_real[pbase + n]);
        float Aim = A_imag[pbase + n];
        float e = expf(Are * dt);
        ar[n] = e * cosf(Aim * dt);               // a = exp(dt*A)
        ai[n] = e * sinf(Aim * dt);
    }

    const float* up = U + (size_t)bh * 4096 + c * 128;
    float pr[32], pi[32];
    #pragma unroll
    for (int n = 0; n < 32; n++) { pr[n] = 0.f; pi[n] = 0.f; }

    // pass 1: local chunk contribution P_c
    for (int j = 0; j < 128; j += 4) {
        float4 u4 = *(const float4*)(up + j);
        float uu[4] = {u4.x, u4.y, u4.z, u4.w};
        #pragma unroll
        for (int q = 0; q < 4; q++) {
            float u = uu[q];
            #pragma unroll
            for (int n = 0; n < 32; n++) {
                float nr = fmaf(ar[n], pr[n], u);
                nr = fmaf(-ai[n], pi[n], nr);
                float ni = ar[n] * pi[n];
                ni = fmaf(ai[n], pr[n], ni);
                pr[n] = nr; pi[n] = ni;
            }
        }
    }

    // m = a^128
    float mr[32], mi[32];
    #pragma unroll
    for (int n = 0; n < 32; n++) {
        float xr = ar[n], xi = ai[n];
        #pragma unroll
        for (int k = 0; k < 7; k++) {
            float nr = xr * xr - xi * xi;
            float ni = 2.f * xr * xi;
            xr = nr; xi = ni;
        }
        mr[n] = xr; mi[n] = xi;
    }

    // inclusive Hillis-Steele scan across the 32 chunk-lanes (width-32 shfl, no LDS)
    #pragma unroll
    for (int d = 1; d < 32; d <<= 1) {
        #pragma unroll
        for (int n = 0; n < 32; n++) {
            float orr = __shfl_up(pr[n], (unsigned)d, 32);
            float oii = __shfl_up(pi[n], (unsigned)d, 32);
            float nr = fmaf(mr[n], orr, pr[n]);
            nr = fmaf(-mi[n], oii, nr);
            float ni = fmaf(mr[n], oii, pi[n]);
            ni = fmaf(mi[n], orr, ni);
            if (c >= d) { pr[n] = nr; pi[n] = ni; }
        }
        if (d < 16) {
            #pragma unroll
            for (int n = 0; n < 32; n++) {
                float nr = mr[n]*mr[n] - mi[n]*mi[n];
                float ni = 2.f*mr[n]*mi[n];
                mr[n] = nr; mi[n] = ni;
            }
        }
    }
    // exclusive: seed for chunk c = inclusive result of chunk c-1
    #pragma unroll
    for (int n = 0; n < 32; n++) {
        float sr_ = __shfl_up(pr[n], 1u, 32);
        float si_ = __shfl_up(pi[n], 1u, 32);
        pr[n] = (c >= 1) ? sr_ : 0.f;
        pi[n] = (c >= 1) ? si_ : 0.f;
    }

    // Ck = C*(a-1)/A
    float ckr[32], cki[32];
    #pragma unroll
    for (int n = 0; n < 32; n++) {
        float Are = -expf(log_A_real[pbase + n]);
        float Aim = A_imag[pbase + n];
        float inv = 1.f / (Are*Are + Aim*Aim);
        float numr = ar[n] - 1.f;
        float numi = ai[n];
        float tr = (numr*Are + numi*Aim) * inv;
        float ti = (numi*Are - numr*Aim) * inv;
        float cr = C_re[pbase + n], ci = C_im[pbase + n];
        ckr[n] = cr*tr - ci*ti;
        cki[n] = cr*ti + ci*tr;
    }

    float Dh = Dp[li * 256 + hh];
    ushort_t* gp = G + (size_t)bhl * 4096 + c * 128;

    // pass 2: seeded scan, emit gelu(2*Re(Ck.s) + D*u) as bf16
    for (int j = 0; j < 128; j += 4) {
        float4 u4 = *(const float4*)(up + j);
        float uu[4] = {u4.x, u4.y, u4.z, u4.w};
        us4 o4;
        ushort_t* os = &o4.x;
        #pragma unroll
        for (int q = 0; q < 4; q++) {
            float u = uu[q];
            #pragma unroll
            for (int n = 0; n < 32; n++) {
                float nr = fmaf(ar[n], pr[n], u);
                nr = fmaf(-ai[n], pi[n], nr);
                float ni = ar[n] * pi[n];
                ni = fmaf(ai[n], pr[n], ni);
                pr[n] = nr; pi[n] = ni;
            }
            float y0 = 0.f, y1 = 0.f, y2 = 0.f, y3 = 0.f;
            #pragma unroll
            for (int n = 0; n < 32; n += 4) {
                y0 = fmaf(ckr[n],   pr[n],   y0); y0 = fmaf(-cki[n],   pi[n],   y0);
                y1 = fmaf(ckr[n+1], pr[n+1], y1); y1 = fmaf(-cki[n+1], pi[n+1], y1);
                y2 = fmaf(ckr[n+2], pr[n+2], y2); y2 = fmaf(-cki[n+2], pi[n+2], y2);
                y3 = fmaf(ckr[n+3], pr[n+3], y3); y3 = fmaf(-cki[n+3], pi[n+3], y3);
            }
            float v = fmaf(Dh, u, 2.f * ((y0+y1)+(y2+y3)));
            float g = v * 0.5f * (1.f + erff(v * 0.70710678118654752f));  // exact gelu
            os[q] = f2bf(g);
        }
        *(us4*)(gp + j) = o4;
    }
}

// ---------------- GLU 1x1 conv (512x256 GEMM, bf16 A / fp32 W) + a*sigmoid(g) + residual ----------------
// grid (NB*64, 2): x = 64-position tile; y = 128-wide o-tile. block 256.
__global__ __launch_bounds__(256, 2) void glu_kernel(
    const ushort_t* __restrict__ G, const float* __restrict__ wT,
    const float* __restrict__ glu_b, float* __restrict__ Hb, int li, int b0)
{
    __shared__ __align__(16) float ytile[16384];  // [hh 256][p 64] fp32
    int t = threadIdx.x;
    int bl0 = blockIdx.x * 64;
    int bloc = bl0 >> 12;                         // batch index local to G chunk
    int l0 = bl0 & 4095;
    int b = b0 + bloc;                            // global batch
    int ot = blockIdx.y;

    const ushort_t* gbase = G + (size_t)bloc * 1048576 + l0;
    #pragma unroll
    for (int i = 0; i < 16; i++) {
        int f = i * 256 + t;
        int row = f >> 4;
        int off = (f & 15) << 2;
        us4 v = *(const us4*)(gbase + (size_t)row * 4096 + off);
        float4 fv;
        fv.x = bf2f(v.x); fv.y = bf2f(v.y); fv.z = bf2f(v.z); fv.w = bf2f(v.w);
        *(float4*)&ytile[row * 64 + off] = fv;
    }
    __syncthreads();

    int tx = t & 31, ty = t >> 5;
    int o0 = ot * 128 + tx * 4;                   // a-channel base (0..255)
    int p0 = ty * 8;

    float acc_a[4][8], acc_g[4][8];
    #pragma unroll
    for (int i = 0; i < 4; i++) {
        float ba = glu_b[li * 512 + o0 + i];
        float bg = glu_b[li * 512 + 256 + o0 + i];
        #pragma unroll
        for (int j = 0; j < 8; j++) { acc_a[i][j] = ba; acc_g[i][j] = bg; }
    }

    const float* wbase = wT + li * 131072;
    for (int hh = 0; hh < 256; hh++) {
        float4 wa  = *(const float4*)(wbase + hh * 512 + o0);
        float4 wg  = *(const float4*)(wbase + hh * 512 + 256 + o0);
        float4 yv0 = *(const float4*)&ytile[hh * 64 + p0];
        float4 yv1 = *(const float4*)&ytile[hh * 64 + p0 + 4];
        float ya[8]  = {yv0.x, yv0.y, yv0.z, yv0.w, yv1.x, yv1.y, yv1.z, yv1.w};
        float was[4] = {wa.x, wa.y, wa.z, wa.w};
        float wgs[4] = {wg.x, wg.y, wg.z, wg.w};
        #pragma unroll
        for (int i = 0; i < 4; i++)
            #pragma unroll
            for (int j = 0; j < 8; j++) {
                acc_a[i][j] = fmaf(was[i], ya[j], acc_a[i][j]);
                acc_g[i][j] = fmaf(wgs[i], ya[j], acc_g[i][j]);
            }
    }

    #pragma unroll
    for (int i = 0; i < 4; i++) {
        float* hp = Hb + (size_t)b * 1048576 + (size_t)(o0 + i) * 4096 + l0 + p0;
        float4 h0 = *(float4*)hp;
        float4 h1 = *(float4*)(hp + 4);
        float z[8];
        #pragma unroll
        for (int j = 0; j < 8; j++) {
            float sg = 1.f / (1.f + expf(-acc_g[i][j]));
            z[j] = acc_a[i][j] * sg;
        }
        h0.x += z[0]; h0.y += z[1]; h0.z += z[2]; h0.w += z[3];
        h1.x += z[4]; h1.y += z[5]; h1.z += z[6]; h1.w += z[7];
        *(float4*)hp = h0;
        *(float4*)(hp + 4) = h1;
    }
}

// ---------------- LayerNorm over H, in place ----------------
__global__ __launch_bounds__(256) void ln_kernel(float* __restrict__ Hb,
    const float* __restrict__ ln_g, const float* __restrict__ ln_b, int li)
{
    int pos = blockIdx.x * 256 + threadIdx.x;     // over B*L
    int b = pos >> 12, l = pos & 4095;
    float* base = Hb + (size_t)b * 1048576 + l;
    float s = 0.f, sq = 0.f;
    #pragma unroll 4
    for (int h = 0; h < 256; h++) {
        float v = base[(size_t)h * 4096];
        s += v; sq = fmaf(v, v, sq);
    }
    float mu = s * (1.f / 256.f);
    float var = sq * (1.f / 256.f) - mu * mu;
    float r = rsqrtf(var + 1e-5f);
    #pragma unroll 4
    for (int h = 0; h < 256; h++) {
        float v = base[(size_t)h * 4096];
        base[(size_t)h * 4096] = (v - mu) * r * ln_g[li * 256 + h] + ln_b[li * 256 + h];
    }
}

// ---------------- decoder ----------------
__global__ __launch_bounds__(256) void dec1_kernel(const float* __restrict__ Hb,
    const float* __restrict__ w1, const float* __restrict__ b1, float* __restrict__ y1)
{
    int bh = blockIdx.x;
    const float* base = Hb + (size_t)bh * 4096;
    int t = threadIdx.x;
    float s = 0.f;
    for (int l = t; l < 4096; l += 256) s = fmaf(base[l], w1[l], s);
    #pragma unroll
    for (int d = 32; d > 0; d >>= 1) s += __shfl_xor(s, d, 64);
    __shared__ float red[4];
    if ((t & 63) == 0) red[t >> 6] = s;
    __syncthreads();
    if (t == 0) y1[bh] = red[0] + red[1] + red[2] + red[3] + b1[0];
}

__global__ __launch_bounds__(256) void dec2_kernel(const float* __restrict__ y1,
    const float* __restrict__ w2, const float* __restrict__ b2, float* __restrict__ out)
{
    int t = threadIdx.x;
    int b = blockIdx.x * 4 + (t >> 6);
    int lane = t & 63;
    float s = 0.f;
    #pragma unroll
    for (int k = 0; k < 4; k++) s = fmaf(y1[b * 256 + lane + k * 64], w2[lane + k * 64], s);
    #pragma unroll
    for (int d = 32; d > 0; d >>= 1) s += __shfl_xor(s, d, 64);
    if (lane == 0) out[b] = 1.f / (1.f + expf(-(s + b2[0])));
}

extern "C" void kernel_launch(void* const* d_in, const int* in_sizes, int n_in,
                              void* d_out, int out_size, void* d_ws, size_t ws_size,
                              hipStream_t stream)
{
    const float* x      = (const float*)d_in[0];
    const float* enc_w  = (const float*)d_in[1];
    const float* enc_b  = (const float*)d_in[2];
    const float* log_dt = (const float*)d_in[3];
    const float* lAr    = (const float*)d_in[4];
    const float* Aim    = (const float*)d_in[5];
    const float* Cre    = (const float*)d_in[6];
    const float* Cim    = (const float*)d_in[7];
    const float* Dp     = (const float*)d_in[8];
    const float* glu_w  = (const float*)d_in[9];
    const float* glu_b  = (const float*)d_in[10];
    const float* ln_g   = (const float*)d_in[11];
    const float* ln_b   = (const float*)d_in[12];
    const float* w1     = (const float*)d_in[13];
    const float* b1     = (const float*)d_in[14];
    const float* w2     = (const float*)d_in[15];
    const float* b2     = (const float*)d_in[16];

    float* ws = (float*)d_ws;
    float* Hb    = ws;
    float* wT    = ws + WS_WT_OFF;
    float* y1    = ws + WS_Y1_OFF;
    ushort_t* Gb = (ushort_t*)(ws + WS_GB_OFF);
    float* outp  = (float*)d_out;

    // Pick G chunk size (batches) from actual ws_size; deterministic per call.
    size_t wsf = ws_size / 4;                      // capacity in floats
    size_t avail_bf16 = (wsf > (size_t)WS_GB_OFF) ? (wsf - WS_GB_OFF) * 2 : 0;
    int nb = 32;
    while (nb > 1 && (size_t)nb * 1048576 > avail_bf16) nb >>= 1;

    wt_kernel<<<2048, 256, 0, stream>>>(glu_w, wT);
    enc_kernel<<<32768, 256, 0, stream>>>(x, enc_w, enc_b, Hb);
    for (int li = 0; li < 4; li++) {
        for (int b0 = 0; b0 < 32; b0 += nb) {
            s4d_kernel<<<nb * 32, 256, 0, stream>>>(Hb, Gb, log_dt, lAr, Aim, Cre, Cim,
                                                    Dp, li, b0 * 256);
            glu_kernel<<<dim3(nb * 64, 2), 256, 0, stream>>>(Gb, wT, glu_b, Hb, li, b0);
        }
        ln_kernel<<<512, 256, 0, stream>>>(Hb, ln_g, ln_b, li);
    }
    dec1_kernel<<<8192, 256, 0, stream>>>(Hb, w1, b1, y1);
    dec2_kernel<<<8, 256, 0, stream>>>(y1, w2, b2, outp);
}

// Round 3
// 2469.870 us; speedup vs baseline: 1.5723x; 1.5723x over previous
//
#include <hip/hip_runtime.h>
#include <math.h>

// Problem constants: B=32, L=4096, CH=1, H=256, NL=4, N2=32
// ws layout (float units):
//   Hb  fp32 (B,H,L)           @ 0          : 33,554,432 floats (128 MiB)
//   wTb bf16 (NL,512,256)      @ 33,554,432 :    262,144 floats (= 524,288 bf16)
//   y1  fp32 (B*H)             @ 33,816,576 :      8,192 floats
//   Gb  bf16 (NB,H,L) chunk    @ 33,824,768 : NB*1,048,576 ushorts
// Full-G (NB=32) high-water: 33,824,768*4 + 67,108,864 = 202,407,936 B (~193 MiB)
#define WS_WT_OFF 33554432
#define WS_Y1_OFF 33816576
#define WS_GB_OFF 33824768

typedef unsigned short ushort_t;
struct us4 { ushort_t x, y, z, w; };
typedef short bf16x8 __attribute__((ext_vector_type(8)));
typedef float f32x4  __attribute__((ext_vector_type(4)));

__device__ __forceinline__ float bf2f(ushort_t u) {
    union { unsigned int i; float f; } c; c.i = ((unsigned int)u) << 16; return c.f;
}
__device__ __forceinline__ ushort_t f2bf(float f) {
    union { float f; unsigned int i; } c; c.f = f;
    unsigned int x = c.i;
    unsigned int r = (x + 0x7FFF + ((x >> 16) & 1)) >> 16;   // RNE
    return (ushort_t)r;
}

// ---------------- encoder ----------------
__global__ __launch_bounds__(256) void enc_kernel(const float* __restrict__ x,
    const float* __restrict__ ew, const float* __restrict__ eb, float* __restrict__ Hb)
{
    int i = blockIdx.x * 256 + threadIdx.x;      // float4 units, 8,388,608 total
    int l4 = i & 1023;
    int h  = (i >> 10) & 255;
    int b  = i >> 18;
    float4 xv = *(const float4*)(x + (b << 12) + (l4 << 2));
    float w = ew[h], bb = eb[h];
    float4 o;
    o.x = fmaf(xv.x, w, bb); o.y = fmaf(xv.y, w, bb);
    o.z = fmaf(xv.z, w, bb); o.w = fmaf(xv.w, w, bb);
    *(float4*)(Hb + ((size_t)i << 2)) = o;
}

// ---------------- weight cast: wTb[li][o][k] = bf16(glu_w[li][o][k]) ----------------
__global__ __launch_bounds__(256) void wtb_kernel(const float* __restrict__ gw, ushort_t* __restrict__ wTb)
{
    int i = blockIdx.x * 256 + threadIdx.x;      // 524,288
    wTb[i] = f2bf(gw[i]);
}

// ---------------- S4D: chunked-scan conv + D skip + exact GELU, bf16 out ----------------
// Each 32-lane group = one (b,h) row; lane = one 128-long chunk of L.
// launch_bounds(256,1): ~290 live VGPRs (pr/pi/ar/ai/ckr/cki = 192) — MUST NOT cap at 128
// (R2: cap caused full spill, WRITE_SIZE 502MB, VALUBusy 5.7%).
__global__ __launch_bounds__(256, 1) void s4d_kernel(
    const float* __restrict__ U, ushort_t* __restrict__ G,
    const float* __restrict__ log_dt, const float* __restrict__ log_A_real,
    const float* __restrict__ A_imag, const float* __restrict__ C_re,
    const float* __restrict__ C_im, const float* __restrict__ Dp, int li, int bh0)
{
    int t = threadIdx.x;
    int grp = t >> 5;
    int c = t & 31;                               // chunk index within row
    int bhl = blockIdx.x * 8 + grp;               // local row within this G chunk
    int bh = bh0 + bhl;                           // global row into Hb
    int hh = bh & 255;
    int pbase = (li * 256 + hh) * 32;

    float dt = expf(log_dt[li * 256 + hh]);
    float ar[32], ai[32];
    #pragma unroll
    for (int n = 0; n < 32; n++) {
        float Are = -expf(log_A_real[pbase + n]);
        float Aim = A_imag[pbase + n];
        float e = expf(Are * dt);
        ar[n] = e * cosf(Aim * dt);               // a = exp(dt*A)
        ai[n] = e * sinf(Aim * dt);
    }

    const float* up = U + (size_t)bh * 4096 + c * 128;
    float pr[32], pi[32];
    #pragma unroll
    for (int n = 0; n < 32; n++) { pr[n] = 0.f; pi[n] = 0.f; }

    // pass 1: local chunk contribution (u prefetched one iter ahead)
    float4 u4 = *(const float4*)(up);
    for (int j = 0; j < 128; j += 4) {
        float4 nxt;
        if (j + 4 < 128) nxt = *(const float4*)(up + j + 4);
        float uu[4] = {u4.x, u4.y, u4.z, u4.w};
        #pragma unroll
        for (int q = 0; q < 4; q++) {
            float u = uu[q];
            #pragma unroll
            for (int n = 0; n < 32; n++) {
                float nr = fmaf(ar[n], pr[n], u);
                nr = fmaf(-ai[n], pi[n], nr);
                float ni = ar[n] * pi[n];
                ni = fmaf(ai[n], pr[n], ni);
                pr[n] = nr; pi[n] = ni;
            }
        }
        u4 = nxt;
    }

    // m = a^128
    float mr[32], mi[32];
    #pragma unroll
    for (int n = 0; n < 32; n++) {
        float xr = ar[n], xi = ai[n];
        #pragma unroll
        for (int k = 0; k < 7; k++) {
            float nr = xr * xr - xi * xi;
            float ni = 2.f * xr * xi;
            xr = nr; xi = ni;
        }
        mr[n] = xr; mi[n] = xi;
    }

    // inclusive Hillis-Steele scan across the 32 chunk-lanes (width-32 shfl, no LDS)
    #pragma unroll
    for (int d = 1; d < 32; d <<= 1) {
        #pragma unroll
        for (int n = 0; n < 32; n++) {
            float orr = __shfl_up(pr[n], (unsigned)d, 32);
            float oii = __shfl_up(pi[n], (unsigned)d, 32);
            float nr = fmaf(mr[n], orr, pr[n]);
            nr = fmaf(-mi[n], oii, nr);
            float ni = fmaf(mr[n], oii, pi[n]);
            ni = fmaf(mi[n], orr, ni);
            if (c >= d) { pr[n] = nr; pi[n] = ni; }
        }
        if (d < 16) {
            #pragma unroll
            for (int n = 0; n < 32; n++) {
                float nr = mr[n]*mr[n] - mi[n]*mi[n];
                float ni = 2.f*mr[n]*mi[n];
                mr[n] = nr; mi[n] = ni;
            }
        }
    }
    // exclusive: seed for chunk c = inclusive result of chunk c-1
    #pragma unroll
    for (int n = 0; n < 32; n++) {
        float sr_ = __shfl_up(pr[n], 1u, 32);
        float si_ = __shfl_up(pi[n], 1u, 32);
        pr[n] = (c >= 1) ? sr_ : 0.f;
        pi[n] = (c >= 1) ? si_ : 0.f;
    }

    // Ck = C*(a-1)/A
    float ckr[32], cki[32];
    #pragma unroll
    for (int n = 0; n < 32; n++) {
        float Are = -expf(log_A_real[pbase + n]);
        float Aim = A_imag[pbase + n];
        float inv = 1.f / (Are*Are + Aim*Aim);
        float numr = ar[n] - 1.f;
        float numi = ai[n];
        float tr = (numr*Are + numi*Aim) * inv;
        float ti = (numi*Are - numr*Aim) * inv;
        float cr = C_re[pbase + n], ci = C_im[pbase + n];
        ckr[n] = cr*tr - ci*ti;
        cki[n] = cr*ti + ci*tr;
    }

    float Dh = Dp[li * 256 + hh];
    ushort_t* gp = G + (size_t)bhl * 4096 + c * 128;

    // pass 2: seeded scan, emit gelu(2*Re(Ck.s) + D*u) as bf16
    u4 = *(const float4*)(up);
    for (int j = 0; j < 128; j += 4) {
        float4 nxt;
        if (j + 4 < 128) nxt = *(const float4*)(up + j + 4);
        float uu[4] = {u4.x, u4.y, u4.z, u4.w};
        us4 o4;
        ushort_t* os = &o4.x;
        #pragma unroll
        for (int q = 0; q < 4; q++) {
            float u = uu[q];
            #pragma unroll
            for (int n = 0; n < 32; n++) {
                float nr = fmaf(ar[n], pr[n], u);
                nr = fmaf(-ai[n], pi[n], nr);
                float ni = ar[n] * pi[n];
                ni = fmaf(ai[n], pr[n], ni);
                pr[n] = nr; pi[n] = ni;
            }
            float y0 = 0.f, y1 = 0.f, y2 = 0.f, y3 = 0.f;
            #pragma unroll
            for (int n = 0; n < 32; n += 4) {
                y0 = fmaf(ckr[n],   pr[n],   y0); y0 = fmaf(-cki[n],   pi[n],   y0);
                y1 = fmaf(ckr[n+1], pr[n+1], y1); y1 = fmaf(-cki[n+1], pi[n+1], y1);
                y2 = fmaf(ckr[n+2], pr[n+2], y2); y2 = fmaf(-cki[n+2], pi[n+2], y2);
                y3 = fmaf(ckr[n+3], pr[n+3], y3); y3 = fmaf(-cki[n+3], pi[n+3], y3);
            }
            float v = fmaf(Dh, u, 2.f * ((y0+y1)+(y2+y3)));
            float g = v * 0.5f * (1.f + erff(v * 0.70710678118654752f));  // exact gelu
            os[q] = f2bf(g);
        }
        *(us4*)(gp + j) = o4;
        u4 = nxt;
    }
}

// ---------------- GLU via bf16 MFMA: z = (Wa.y+ba) * sigmoid(Wg.y+bg), Hb += z ----------
// Block = 256 thr (4 waves), p-tile = 64 positions (one b), M = all 512 rows of W.
// Wave w owns a-channels [64w,64w+64) and g-channels [256+64w, ...): sigmoid pairing in-wave.
// G tile is register-transposed into LDS [p][k] (k padded 256->268).
#define LDK 268
__global__ __launch_bounds__(256, 2) void glu_kernel(
    const ushort_t* __restrict__ G, const ushort_t* __restrict__ wTb,
    const float* __restrict__ glu_b, float* __restrict__ Hb, int li, int b0)
{
    __shared__ ushort_t yt[64 * LDK];             // 34,304 B
    int t = threadIdx.x;
    int pf = blockIdx.x * 64;
    int bloc = pf >> 12;                          // batch local to G chunk
    int l0 = pf & 4095;
    int b = b0 + bloc;

    const ushort_t* gb = G + (size_t)bloc * 1048576 + l0;
    unsigned int* dst = (unsigned int*)&yt[0];
    #pragma unroll
    for (int i = 0; i < 4; i++) {
        int flat = i * 256 + t;
        int hp = flat >> 3;                       // 0..127 (h pair)
        int pg = flat & 7;                        // 0..7 (p group of 8)
        int h0 = hp * 2;
        uint4 va = *(const uint4*)(gb + (size_t)h0 * 4096 + pg * 8);
        uint4 vb = *(const uint4*)(gb + (size_t)(h0 + 1) * 4096 + pg * 8);
        const ushort_t* ra = (const ushort_t*)&va;
        const ushort_t* rb = (const ushort_t*)&vb;
        #pragma unroll
        for (int j = 0; j < 8; j++) {
            unsigned int v = (unsigned int)ra[j] | ((unsigned int)rb[j] << 16);
            dst[(pg * 8 + j) * (LDK / 2) + hp] = v;   // yt[p][k=h0] as dword pair
        }
    }
    __syncthreads();

    int lane = t & 63, w = t >> 6;
    int ln15 = lane & 15, quad = lane >> 4;
    int oA = w * 64;
    const ushort_t* wA = wTb + li * 131072;

    f32x4 accA[4][4] = {};
    f32x4 accG[4][4] = {};

    for (int ks = 0; ks < 8; ks++) {
        int kk = ks * 32 + quad * 8;
        bf16x8 af[4], gf[4];
        #pragma unroll
        for (int mt = 0; mt < 4; mt++) {
            int oa = oA + mt * 16 + ln15;
            af[mt] = *(const bf16x8*)(wA + (size_t)oa * 256 + kk);
            gf[mt] = *(const bf16x8*)(wA + (size_t)(oa + 256) * 256 + kk);
        }
        bf16x8 bfr[4];
        #pragma unroll
        for (int nt = 0; nt < 4; nt++) {
            const us4* yp = (const us4*)&yt[(nt * 16 + ln15) * LDK + kk]; // 8B-aligned
            us4 lo = yp[0], hi = yp[1];
            bf16x8 v;
            v[0] = (short)lo.x; v[1] = (short)lo.y; v[2] = (short)lo.z; v[3] = (short)lo.w;
            v[4] = (short)hi.x; v[5] = (short)hi.y; v[6] = (short)hi.z; v[7] = (short)hi.w;
            bfr[nt] = v;
        }
        #pragma unroll
        for (int mt = 0; mt < 4; mt++)
            #pragma unroll
            for (int nt = 0; nt < 4; nt++) {
                accA[mt][nt] = __builtin_amdgcn_mfma_f32_16x16x32_bf16(af[mt], bfr[nt], accA[mt][nt], 0, 0, 0);
                accG[mt][nt] = __builtin_amdgcn_mfma_f32_16x16x32_bf16(gf[mt], bfr[nt], accG[mt][nt], 0, 0, 0);
            }
    }

    // epilogue: C/D layout (m89): col = lane&15 (p), row = quad*4 + r (o)
    #pragma unroll
    for (int mt = 0; mt < 4; mt++) {
        #pragma unroll
        for (int r = 0; r < 4; r++) {
            int o = oA + mt * 16 + quad * 4 + r;
            float ba = glu_b[li * 512 + o];
            float bg = glu_b[li * 512 + 256 + o];
            float* hrow = Hb + (size_t)b * 1048576 + (size_t)o * 4096 + l0 + ln15;
            #pragma unroll
            for (int nt = 0; nt < 4; nt++) {
                float a = accA[mt][nt][r] + ba;
                float g = accG[mt][nt][r] + bg;
                float z = a / (1.f + expf(-g));
                hrow[nt * 16] += z;
            }
        }
    }
}

// ---------------- LayerNorm over H, in place ----------------
__global__ __launch_bounds__(256) void ln_kernel(float* __restrict__ Hb,
    const float* __restrict__ ln_g, const float* __restrict__ ln_b, int li)
{
    int pos = blockIdx.x * 256 + threadIdx.x;     // over B*L
    int b = pos >> 12, l = pos & 4095;
    float* base = Hb + (size_t)b * 1048576 + l;
    float s = 0.f, sq = 0.f;
    #pragma unroll 4
    for (int h = 0; h < 256; h++) {
        float v = base[(size_t)h * 4096];
        s += v; sq = fmaf(v, v, sq);
    }
    float mu = s * (1.f / 256.f);
    float var = sq * (1.f / 256.f) - mu * mu;
    float r = rsqrtf(var + 1e-5f);
    #pragma unroll 4
    for (int h = 0; h < 256; h++) {
        float v = base[(size_t)h * 4096];
        base[(size_t)h * 4096] = (v - mu) * r * ln_g[li * 256 + h] + ln_b[li * 256 + h];
    }
}

// ---------------- decoder ----------------
__global__ __launch_bounds__(256) void dec1_kernel(const float* __restrict__ Hb,
    const float* __restrict__ w1, const float* __restrict__ b1, float* __restrict__ y1)
{
    int bh = blockIdx.x;
    const float* base = Hb + (size_t)bh * 4096;
    int t = threadIdx.x;
    float s = 0.f;
    for (int l = t; l < 4096; l += 256) s = fmaf(base[l], w1[l], s);
    #pragma unroll
    for (int d = 32; d > 0; d >>= 1) s += __shfl_xor(s, d, 64);
    __shared__ float red[4];
    if ((t & 63) == 0) red[t >> 6] = s;
    __syncthreads();
    if (t == 0) y1[bh] = red[0] + red[1] + red[2] + red[3] + b1[0];
}

__global__ __launch_bounds__(256) void dec2_kernel(const float* __restrict__ y1,
    const float* __restrict__ w2, const float* __restrict__ b2, float* __restrict__ out)
{
    int t = threadIdx.x;
    int b = blockIdx.x * 4 + (t >> 6);
    int lane = t & 63;
    float s = 0.f;
    #pragma unroll
    for (int k = 0; k < 4; k++) s = fmaf(y1[b * 256 + lane + k * 64], w2[lane + k * 64], s);
    #pragma unroll
    for (int d = 32; d > 0; d >>= 1) s += __shfl_xor(s, d, 64);
    if (lane == 0) out[b] = 1.f / (1.f + expf(-(s + b2[0])));
}

extern "C" void kernel_launch(void* const* d_in, const int* in_sizes, int n_in,
                              void* d_out, int out_size, void* d_ws, size_t ws_size,
                              hipStream_t stream)
{
    const float* x      = (const float*)d_in[0];
    const float* enc_w  = (const float*)d_in[1];
    const float* enc_b  = (const float*)d_in[2];
    const float* log_dt = (const float*)d_in[3];
    const float* lAr    = (const float*)d_in[4];
    const float* Aim    = (const float*)d_in[5];
    const float* Cre    = (const float*)d_in[6];
    const float* Cim    = (const float*)d_in[7];
    const float* Dp     = (const float*)d_in[8];
    const float* glu_w  = (const float*)d_in[9];
    const float* glu_b  = (const float*)d_in[10];
    const float* ln_g   = (const float*)d_in[11];
    const float* ln_b   = (const float*)d_in[12];
    const float* w1     = (const float*)d_in[13];
    const float* b1     = (const float*)d_in[14];
    const float* w2     = (const float*)d_in[15];
    const float* b2     = (const float*)d_in[16];

    float* ws = (float*)d_ws;
    float* Hb     = ws;
    ushort_t* wTb = (ushort_t*)(ws + WS_WT_OFF);
    float* y1     = ws + WS_Y1_OFF;
    ushort_t* Gb  = (ushort_t*)(ws + WS_GB_OFF);
    float* outp   = (float*)d_out;

    // Pick G chunk size (batches) from actual ws_size; deterministic per call.
    size_t wsf = ws_size / 4;
    size_t avail_bf16 = (wsf > (size_t)WS_GB_OFF) ? (wsf - WS_GB_OFF) * 2 : 0;
    int nb = 32;
    while (nb > 1 && (size_t)nb * 1048576 > avail_bf16) nb >>= 1;

    wtb_kernel<<<2048, 256, 0, stream>>>(glu_w, wTb);
    enc_kernel<<<32768, 256, 0, stream>>>(x, enc_w, enc_b, Hb);
    for (int li = 0; li < 4; li++) {
        for (int b0 = 0; b0 < 32; b0 += nb) {
            s4d_kernel<<<nb * 32, 256, 0, stream>>>(Hb, Gb, log_dt, lAr, Aim, Cre, Cim,
                                                    Dp, li, b0 * 256);
            glu_kernel<<<nb * 64, 256, 0, stream>>>(Gb, wTb, glu_b, Hb, li, b0);
        }
        ln_kernel<<<512, 256, 0, stream>>>(Hb, ln_g, ln_b, li);
    }
    dec1_kernel<<<8192, 256, 0, stream>>>(Hb, w1, b1, y1);
    dec2_kernel<<<8, 256, 0, stream>>>(y1, w2, b2, outp);
}

// Round 4
// 2086.178 us; speedup vs baseline: 1.8615x; 1.1839x over previous
//
#include <hip/hip_runtime.h>
#include <math.h>

// Problem constants: B=32, L=4096, CH=1, H=256, NL=4, N2=32
// ws layout (float units):
//   Hb  fp32 (B,H,L)           @ 0          : 33,554,432 floats (128 MiB)
//   wTb bf16 (NL,512,256)      @ 33,554,432 :    262,144 floats (= 524,288 bf16)
//   y1  fp32 (B*H)             @ 33,816,576 :      8,192 floats
//   Gb  bf16 (NB,H,L) chunk    @ 33,824,768 : NB*1,048,576 ushorts
// Full-G (NB=32) high-water: 33,824,768*4 + 67,108,864 = 202,407,936 B (~193 MiB)
#define WS_WT_OFF 33554432
#define WS_Y1_OFF 33816576
#define WS_GB_OFF 33824768

typedef unsigned short ushort_t;
struct us4 { ushort_t x, y, z, w; };
typedef short bf16x8 __attribute__((ext_vector_type(8)));
typedef float f32x4  __attribute__((ext_vector_type(4)));

__device__ __forceinline__ float bf2f(ushort_t u) {
    union { unsigned int i; float f; } c; c.i = ((unsigned int)u) << 16; return c.f;
}
__device__ __forceinline__ ushort_t f2bf(float f) {
    union { float f; unsigned int i; } c; c.f = f;
    unsigned int x = c.i;
    unsigned int r = (x + 0x7FFF + ((x >> 16) & 1)) >> 16;   // RNE
    return (ushort_t)r;
}

// ---------------- encoder ----------------
__global__ __launch_bounds__(256) void enc_kernel(const float* __restrict__ x,
    const float* __restrict__ ew, const float* __restrict__ eb, float* __restrict__ Hb)
{
    int i = blockIdx.x * 256 + threadIdx.x;      // float4 units, 8,388,608 total
    int l4 = i & 1023;
    int h  = (i >> 10) & 255;
    int b  = i >> 18;
    float4 xv = *(const float4*)(x + (b << 12) + (l4 << 2));
    float w = ew[h], bb = eb[h];
    float4 o;
    o.x = fmaf(xv.x, w, bb); o.y = fmaf(xv.y, w, bb);
    o.z = fmaf(xv.z, w, bb); o.w = fmaf(xv.w, w, bb);
    *(float4*)(Hb + ((size_t)i << 2)) = o;
}

// ---------------- weight cast: wTb[li][o][k] = bf16(glu_w[li][o][k]) ----------------
__global__ __launch_bounds__(256) void wtb_kernel(const float* __restrict__ gw, ushort_t* __restrict__ wTb)
{
    int i = blockIdx.x * 256 + threadIdx.x;      // 524,288
    wTb[i] = f2bf(gw[i]);
}

// ---------------- S4D: chunked-scan conv + D skip + exact GELU, bf16 out ----------------
// One 64-lane wave per (b,h) row. States split across wave halves:
//   half = lane>>5 owns states [16*half, 16*half+16); c = lane&31 = chunk of 128 steps.
// This halves per-lane register demand vs R3 (which spilled 300MB/layer at VGPR=160).
// Width-32 shuffles keep the scan inside each half; pass-2 dot combined via shfl_xor(32).
__global__ __launch_bounds__(256, 3) void s4d_kernel(
    const float* __restrict__ U, ushort_t* __restrict__ G,
    const float* __restrict__ log_dt, const float* __restrict__ log_A_real,
    const float* __restrict__ A_imag, const float* __restrict__ C_re,
    const float* __restrict__ C_im, const float* __restrict__ Dp, int li, int bh0)
{
    int t = threadIdx.x;
    int wid = t >> 6;                             // wave = row
    int lane = t & 63;
    int half = lane >> 5;
    int c = lane & 31;                            // chunk index
    int bhl = blockIdx.x * 4 + wid;               // local row within this G chunk
    int bh = bh0 + bhl;                           // global row into Hb
    int hh = bh & 255;
    int pb = (li * 256 + hh) * 32 + half * 16;

    float dt = expf(log_dt[li * 256 + hh]);
    float ar[16], ai[16];
    #pragma unroll
    for (int n = 0; n < 16; n++) {
        float Are = -expf(log_A_real[pb + n]);
        float Aim = A_imag[pb + n];
        float e = expf(Are * dt);
        ar[n] = e * cosf(Aim * dt);               // a = exp(dt*A)
        ai[n] = e * sinf(Aim * dt);
    }

    const float* up = U + (size_t)bh * 4096 + c * 128;
    float pr[16], pi[16];
    #pragma unroll
    for (int n = 0; n < 16; n++) { pr[n] = 0.f; pi[n] = 0.f; }

    // pass 1: local chunk contribution (u prefetched one iter ahead)
    float4 u4 = *(const float4*)(up);
    for (int j = 0; j < 128; j += 4) {
        float4 nxt;
        if (j + 4 < 128) nxt = *(const float4*)(up + j + 4);
        float uu[4] = {u4.x, u4.y, u4.z, u4.w};
        #pragma unroll
        for (int q = 0; q < 4; q++) {
            float u = uu[q];
            #pragma unroll
            for (int n = 0; n < 16; n++) {
                float nr = fmaf(ar[n], pr[n], u);
                nr = fmaf(-ai[n], pi[n], nr);
                float ni = ar[n] * pi[n];
                ni = fmaf(ai[n], pr[n], ni);
                pr[n] = nr; pi[n] = ni;
            }
        }
        u4 = nxt;
    }

    // m = a^128
    float mr[16], mi[16];
    #pragma unroll
    for (int n = 0; n < 16; n++) {
        float xr = ar[n], xi = ai[n];
        #pragma unroll
        for (int k = 0; k < 7; k++) {
            float nr = xr * xr - xi * xi;
            float ni = 2.f * xr * xi;
            xr = nr; xi = ni;
        }
        mr[n] = xr; mi[n] = xi;
    }

    // inclusive Hillis-Steele scan across the 32 chunk-lanes of each half-wave
    #pragma unroll
    for (int d = 1; d < 32; d <<= 1) {
        #pragma unroll
        for (int n = 0; n < 16; n++) {
            float orr = __shfl_up(pr[n], (unsigned)d, 32);
            float oii = __shfl_up(pi[n], (unsigned)d, 32);
            float nr = fmaf(mr[n], orr, pr[n]);
            nr = fmaf(-mi[n], oii, nr);
            float ni = fmaf(mr[n], oii, pi[n]);
            ni = fmaf(mi[n], orr, ni);
            if (c >= d) { pr[n] = nr; pi[n] = ni; }
        }
        if (d < 16) {
            #pragma unroll
            for (int n = 0; n < 16; n++) {
                float nr = mr[n]*mr[n] - mi[n]*mi[n];
                float ni = 2.f*mr[n]*mi[n];
                mr[n] = nr; mi[n] = ni;
            }
        }
    }
    // exclusive: seed for chunk c = inclusive result of chunk c-1
    #pragma unroll
    for (int n = 0; n < 16; n++) {
        float sr_ = __shfl_up(pr[n], 1u, 32);
        float si_ = __shfl_up(pi[n], 1u, 32);
        pr[n] = (c >= 1) ? sr_ : 0.f;
        pi[n] = (c >= 1) ? si_ : 0.f;
    }

    // Ck = C*(a-1)/A
    float ckr[16], cki[16];
    #pragma unroll
    for (int n = 0; n < 16; n++) {
        float Are = -expf(log_A_real[pb + n]);
        float Aim = A_imag[pb + n];
        float inv = 1.f / (Are*Are + Aim*Aim);
        float numr = ar[n] - 1.f;
        float numi = ai[n];
        float tr = (numr*Are + numi*Aim) * inv;
        float ti = (numi*Are - numr*Aim) * inv;
        float cr = C_re[pb + n], ci = C_im[pb + n];
        ckr[n] = cr*tr - ci*ti;
        cki[n] = cr*ti + ci*tr;
    }

    float Dh = Dp[li * 256 + hh];
    ushort_t* gp = G + (size_t)bhl * 4096 + c * 128;

    // pass 2: seeded scan; y = half-dot, combined across halves via shfl_xor(32)
    u4 = *(const float4*)(up);
    for (int j = 0; j < 128; j += 4) {
        float4 nxt;
        if (j + 4 < 128) nxt = *(const float4*)(up + j + 4);
        float uu[4] = {u4.x, u4.y, u4.z, u4.w};
        float ys[4];
        #pragma unroll
        for (int q = 0; q < 4; q++) {
            float u = uu[q];
            #pragma unroll
            for (int n = 0; n < 16; n++) {
                float nr = fmaf(ar[n], pr[n], u);
                nr = fmaf(-ai[n], pi[n], nr);
                float ni = ar[n] * pi[n];
                ni = fmaf(ai[n], pr[n], ni);
                pr[n] = nr; pi[n] = ni;
            }
            float y0 = 0.f, y1 = 0.f, y2 = 0.f, y3 = 0.f;
            #pragma unroll
            for (int n = 0; n < 16; n += 4) {
                y0 = fmaf(ckr[n],   pr[n],   y0); y0 = fmaf(-cki[n],   pi[n],   y0);
                y1 = fmaf(ckr[n+1], pr[n+1], y1); y1 = fmaf(-cki[n+1], pi[n+1], y1);
                y2 = fmaf(ckr[n+2], pr[n+2], y2); y2 = fmaf(-cki[n+2], pi[n+2], y2);
                y3 = fmaf(ckr[n+3], pr[n+3], y3); y3 = fmaf(-cki[n+3], pi[n+3], y3);
            }
            ys[q] = (y0 + y1) + (y2 + y3);
        }
        us4 o4;
        ushort_t* os = &o4.x;
        #pragma unroll
        for (int q = 0; q < 4; q++) {
            float yo = ys[q] + __shfl_xor(ys[q], 32, 64);
            float v = fmaf(Dh, uu[q], 2.f * yo);
            float g = v * 0.5f * (1.f + erff(v * 0.70710678118654752f));  // exact gelu
            os[q] = f2bf(g);
        }
        if (half == 0) *(us4*)(gp + j) = o4;
        u4 = nxt;
    }
}

// ---------------- GLU via bf16 MFMA: z = (Wa.y+ba) * sigmoid(Wg.y+bg), Hb += z ----------
// Block = 256 thr (4 waves), p-tile = 64 positions (one b), M = all 512 rows of W.
// Wave w owns a-channels [64w,64w+64) and g-channels [256+64w, ...): sigmoid pairing in-wave.
// G tile is register-transposed into LDS [p][k] (k padded 256->268).
#define LDK 268
__global__ __launch_bounds__(256, 2) void glu_kernel(
    const ushort_t* __restrict__ G, const ushort_t* __restrict__ wTb,
    const float* __restrict__ glu_b, float* __restrict__ Hb, int li, int b0)
{
    __shared__ ushort_t yt[64 * LDK];             // 34,304 B
    int t = threadIdx.x;
    int pf = blockIdx.x * 64;
    int bloc = pf >> 12;                          // batch local to G chunk
    int l0 = pf & 4095;
    int b = b0 + bloc;

    const ushort_t* gb = G + (size_t)bloc * 1048576 + l0;
    unsigned int* dst = (unsigned int*)&yt[0];
    #pragma unroll
    for (int i = 0; i < 4; i++) {
        int flat = i * 256 + t;
        int hp = flat >> 3;                       // 0..127 (h pair)
        int pg = flat & 7;                        // 0..7 (p group of 8)
        int h0 = hp * 2;
        uint4 va = *(const uint4*)(gb + (size_t)h0 * 4096 + pg * 8);
        uint4 vb = *(const uint4*)(gb + (size_t)(h0 + 1) * 4096 + pg * 8);
        const ushort_t* ra = (const ushort_t*)&va;
        const ushort_t* rb = (const ushort_t*)&vb;
        #pragma unroll
        for (int j = 0; j < 8; j++) {
            unsigned int v = (unsigned int)ra[j] | ((unsigned int)rb[j] << 16);
            dst[(pg * 8 + j) * (LDK / 2) + hp] = v;   // yt[p][k=h0] as dword pair
        }
    }
    __syncthreads();

    int lane = t & 63, w = t >> 6;
    int ln15 = lane & 15, quad = lane >> 4;
    int oA = w * 64;
    const ushort_t* wA = wTb + li * 131072;

    f32x4 accA[4][4] = {};
    f32x4 accG[4][4] = {};

    for (int ks = 0; ks < 8; ks++) {
        int kk = ks * 32 + quad * 8;
        bf16x8 af[4], gf[4];
        #pragma unroll
        for (int mt = 0; mt < 4; mt++) {
            int oa = oA + mt * 16 + ln15;
            af[mt] = *(const bf16x8*)(wA + (size_t)oa * 256 + kk);
            gf[mt] = *(const bf16x8*)(wA + (size_t)(oa + 256) * 256 + kk);
        }
        bf16x8 bfr[4];
        #pragma unroll
        for (int nt = 0; nt < 4; nt++) {
            const us4* yp = (const us4*)&yt[(nt * 16 + ln15) * LDK + kk]; // 8B-aligned
            us4 lo = yp[0], hi = yp[1];
            bf16x8 v;
            v[0] = (short)lo.x; v[1] = (short)lo.y; v[2] = (short)lo.z; v[3] = (short)lo.w;
            v[4] = (short)hi.x; v[5] = (short)hi.y; v[6] = (short)hi.z; v[7] = (short)hi.w;
            bfr[nt] = v;
        }
        #pragma unroll
        for (int mt = 0; mt < 4; mt++)
            #pragma unroll
            for (int nt = 0; nt < 4; nt++) {
                accA[mt][nt] = __builtin_amdgcn_mfma_f32_16x16x32_bf16(af[mt], bfr[nt], accA[mt][nt], 0, 0, 0);
                accG[mt][nt] = __builtin_amdgcn_mfma_f32_16x16x32_bf16(gf[mt], bfr[nt], accG[mt][nt], 0, 0, 0);
            }
    }

    // epilogue: C/D layout (m89): col = lane&15 (p), row = quad*4 + r (o)
    #pragma unroll
    for (int mt = 0; mt < 4; mt++) {
        #pragma unroll
        for (int r = 0; r < 4; r++) {
            int o = oA + mt * 16 + quad * 4 + r;
            float ba = glu_b[li * 512 + o];
            float bg = glu_b[li * 512 + 256 + o];
            float* hrow = Hb + (size_t)b * 1048576 + (size_t)o * 4096 + l0 + ln15;
            #pragma unroll
            for (int nt = 0; nt < 4; nt++) {
                float a = accA[mt][nt][r] + ba;
                float g = accG[mt][nt][r] + bg;
                float z = a / (1.f + expf(-g));
                hrow[nt * 16] += z;
            }
        }
    }
}

// ---------------- LayerNorm over H, in place, single global read ----------------
// Block = 64 positions x 4 h-quarters. Thread (q,p) keeps its 64 h-values in regs.
__global__ __launch_bounds__(256) void ln_kernel(float* __restrict__ Hb,
    const float* __restrict__ ln_g, const float* __restrict__ ln_b, int li)
{
    __shared__ float sred[4][64], sqred[4][64];
    __shared__ float gs[256], bs[256];
    int t = threadIdx.x;
    int q = t >> 6, p = t & 63;
    int pos0 = blockIdx.x * 64;                   // 2048 blocks over B*L
    int b = pos0 >> 12, l0 = pos0 & 4095;
    float* base = Hb + (size_t)b * 1048576 + (size_t)q * 64 * 4096 + l0 + p;

    gs[t] = ln_g[li * 256 + t];
    bs[t] = ln_b[li * 256 + t];

    float v[64];
    float s = 0.f, sq = 0.f;
    #pragma unroll
    for (int j = 0; j < 64; j++) {
        v[j] = base[(size_t)j * 4096];
        s += v[j]; sq = fmaf(v[j], v[j], sq);
    }
    sred[q][p] = s; sqred[q][p] = sq;
    __syncthreads();
    float S  = (sred[0][p]  + sred[1][p])  + (sred[2][p]  + sred[3][p]);
    float SQ = (sqred[0][p] + sqred[1][p]) + (sqred[2][p] + sqred[3][p]);
    float mu = S * (1.f / 256.f);
    float var = SQ * (1.f / 256.f) - mu * mu;
    float r = rsqrtf(var + 1e-5f);
    #pragma unroll
    for (int j = 0; j < 64; j++) {
        int h = q * 64 + j;
        base[(size_t)j * 4096] = (v[j] - mu) * r * gs[h] + bs[h];
    }
}

// ---------------- decoder ----------------
__global__ __launch_bounds__(256) void dec1_kernel(const float* __restrict__ Hb,
    const float* __restrict__ w1, const float* __restrict__ b1, float* __restrict__ y1)
{
    int bh = blockIdx.x;
    const float* base = Hb + (size_t)bh * 4096;
    int t = threadIdx.x;
    float s = 0.f;
    for (int l = t; l < 4096; l += 256) s = fmaf(base[l], w1[l], s);
    #pragma unroll
    for (int d = 32; d > 0; d >>= 1) s += __shfl_xor(s, d, 64);
    __shared__ float red[4];
    if ((t & 63) == 0) red[t >> 6] = s;
    __syncthreads();
    if (t == 0) y1[bh] = red[0] + red[1] + red[2] + red[3] + b1[0];
}

__global__ __launch_bounds__(256) void dec2_kernel(const float* __restrict__ y1,
    const float* __restrict__ w2, const float* __restrict__ b2, float* __restrict__ out)
{
    int t = threadIdx.x;
    int b = blockIdx.x * 4 + (t >> 6);
    int lane = t & 63;
    float s = 0.f;
    #pragma unroll
    for (int k = 0; k < 4; k++) s = fmaf(y1[b * 256 + lane + k * 64], w2[lane + k * 64], s);
    #pragma unroll
    for (int d = 32; d > 0; d >>= 1) s += __shfl_xor(s, d, 64);
    if (lane == 0) out[b] = 1.f / (1.f + expf(-(s + b2[0])));
}

extern "C" void kernel_launch(void* const* d_in, const int* in_sizes, int n_in,
                              void* d_out, int out_size, void* d_ws, size_t ws_size,
                              hipStream_t stream)
{
    const float* x      = (const float*)d_in[0];
    const float* enc_w  = (const float*)d_in[1];
    const float* enc_b  = (const float*)d_in[2];
    const float* log_dt = (const float*)d_in[3];
    const float* lAr    = (const float*)d_in[4];
    const float* Aim    = (const float*)d_in[5];
    const float* Cre    = (const float*)d_in[6];
    const float* Cim    = (const float*)d_in[7];
    const float* Dp     = (const float*)d_in[8];
    const float* glu_w  = (const float*)d_in[9];
    const float* glu_b  = (const float*)d_in[10];
    const float* ln_g   = (const float*)d_in[11];
    const float* ln_b   = (const float*)d_in[12];
    const float* w1     = (const float*)d_in[13];
    const float* b1     = (const float*)d_in[14];
    const float* w2     = (const float*)d_in[15];
    const float* b2     = (const float*)d_in[16];

    float* ws = (float*)d_ws;
    float* Hb     = ws;
    ushort_t* wTb = (ushort_t*)(ws + WS_WT_OFF);
    float* y1     = ws + WS_Y1_OFF;
    ushort_t* Gb  = (ushort_t*)(ws + WS_GB_OFF);
    float* outp   = (float*)d_out;

    // Pick G chunk size (batches) from actual ws_size; deterministic per call.
    size_t wsf = ws_size / 4;
    size_t avail_bf16 = (wsf > (size_t)WS_GB_OFF) ? (wsf - WS_GB_OFF) * 2 : 0;
    int nb = 32;
    while (nb > 1 && (size_t)nb * 1048576 > avail_bf16) nb >>= 1;

    wtb_kernel<<<2048, 256, 0, stream>>>(glu_w, wTb);
    enc_kernel<<<32768, 256, 0, stream>>>(x, enc_w, enc_b, Hb);
    for (int li = 0; li < 4; li++) {
        for (int b0 = 0; b0 < 32; b0 += nb) {
            s4d_kernel<<<nb * 64, 256, 0, stream>>>(Hb, Gb, log_dt, lAr, Aim, Cre, Cim,
                                                    Dp, li, b0 * 256);
            glu_kernel<<<nb * 64, 256, 0, stream>>>(Gb, wTb, glu_b, Hb, li, b0);
        }
        ln_kernel<<<2048, 256, 0, stream>>>(Hb, ln_g, ln_b, li);
    }
    dec1_kernel<<<8192, 256, 0, stream>>>(Hb, w1, b1, y1);
    dec2_kernel<<<8, 256, 0, stream>>>(y1, w2, b2, outp);
}

// Round 5
// 1936.300 us; speedup vs baseline: 2.0056x; 1.0774x over previous
//
#include <hip/hip_runtime.h>
#include <math.h>

// Problem constants: B=32, L=4096, CH=1, H=256, NL=4, N2=32
// ws layout (float units):
//   Hb  fp32 (B,H,L)           @ 0          : 33,554,432 floats (128 MiB)
//   wTb bf16 (NL,512,256)      @ 33,554,432 :    262,144 floats (= 524,288 bf16)
//   y1  fp32 (B*H)             @ 33,816,576 :      8,192 floats
//   Gb  bf16 (NB,H,L) chunk    @ 33,824,768 : NB*1,048,576 ushorts
// Full-G (NB=32) high-water: 33,824,768*4 + 67,108,864 = 202,407,936 B (~193 MiB)
#define WS_WT_OFF 33554432
#define WS_Y1_OFF 33816576
#define WS_GB_OFF 33824768

typedef unsigned short ushort_t;
struct us4 { ushort_t x, y, z, w; };
typedef short bf16x8 __attribute__((ext_vector_type(8)));
typedef float f32x4  __attribute__((ext_vector_type(4)));

__device__ __forceinline__ float bf2f(ushort_t u) {
    union { unsigned int i; float f; } c; c.i = ((unsigned int)u) << 16; return c.f;
}
__device__ __forceinline__ ushort_t f2bf(float f) {
    union { float f; unsigned int i; } c; c.f = f;
    unsigned int x = c.i;
    unsigned int r = (x + 0x7FFF + ((x >> 16) & 1)) >> 16;   // RNE
    return (ushort_t)r;
}

// ---------------- encoder ----------------
__global__ __launch_bounds__(256) void enc_kernel(const float* __restrict__ x,
    const float* __restrict__ ew, const float* __restrict__ eb, float* __restrict__ Hb)
{
    int i = blockIdx.x * 256 + threadIdx.x;      // float4 units, 8,388,608 total
    int l4 = i & 1023;
    int h  = (i >> 10) & 255;
    int b  = i >> 18;
    float4 xv = *(const float4*)(x + (b << 12) + (l4 << 2));
    float w = ew[h], bb = eb[h];
    float4 o;
    o.x = fmaf(xv.x, w, bb); o.y = fmaf(xv.y, w, bb);
    o.z = fmaf(xv.z, w, bb); o.w = fmaf(xv.w, w, bb);
    *(float4*)(Hb + ((size_t)i << 2)) = o;
}

// ---------------- weight cast: wTb[li][o][k] = bf16(glu_w[li][o][k]) ----------------
__global__ __launch_bounds__(256) void wtb_kernel(const float* __restrict__ gw, ushort_t* __restrict__ wTb)
{
    int i = blockIdx.x * 256 + threadIdx.x;      // 524,288
    wTb[i] = f2bf(gw[i]);
}

// ---------------- S4D: chunked-scan conv + D skip + exact GELU, bf16 out ----------------
// One 64-lane wave per (b,h) row. Lane = c*4+g: c in [0,16) = chunk of 256 steps,
// g in [0,4) = state group of 8 (states [8g, 8g+8)).
// Per-lane arrays are 8 floats -> peak live ~70 VGPR, no spill (R4 at 16/lane spilled
// 180MB/launch through AGPR/scratch; R3 at 32/lane spilled 300MB).
// Scan over chunks: shfl_up stride 4d (g preserved). Pass-2 dot combined across the
// 4 g-lanes of a chunk via shfl_xor(1)+shfl_xor(2); lane g gelus+stores step j+g.
__global__ __launch_bounds__(256, 4) void s4d_kernel(
    const float* __restrict__ U, ushort_t* __restrict__ G,
    const float* __restrict__ log_dt, const float* __restrict__ log_A_real,
    const float* __restrict__ A_imag, const float* __restrict__ C_re,
    const float* __restrict__ C_im, const float* __restrict__ Dp, int li, int bh0)
{
    int t = threadIdx.x;
    int wid = t >> 6;                             // wave = row
    int lane = t & 63;
    int c = lane >> 2;                            // chunk index [0,16)
    int g = lane & 3;                             // state group [0,4)
    int bhl = blockIdx.x * 4 + wid;               // local row within this G chunk
    int bh = bh0 + bhl;                           // global row into Hb
    int hh = bh & 255;
    int pb = (li * 256 + hh) * 32 + g * 8;

    float dt = expf(log_dt[li * 256 + hh]);
    float ar[8], ai[8];
    #pragma unroll
    for (int n = 0; n < 8; n++) {
        float Are = -expf(log_A_real[pb + n]);
        float Aim = A_imag[pb + n];
        float e = expf(Are * dt);
        ar[n] = e * cosf(Aim * dt);               // a = exp(dt*A)
        ai[n] = e * sinf(Aim * dt);
    }

    const float* up = U + (size_t)bh * 4096 + c * 256;
    float pr[8], pi[8];
    #pragma unroll
    for (int n = 0; n < 8; n++) { pr[n] = 0.f; pi[n] = 0.f; }

    // pass 1: local chunk contribution (u prefetched one iter ahead)
    float4 u4 = *(const float4*)(up);
    for (int j = 0; j < 256; j += 4) {
        float4 nxt;
        if (j + 4 < 256) nxt = *(const float4*)(up + j + 4);
        float uu[4] = {u4.x, u4.y, u4.z, u4.w};
        #pragma unroll
        for (int q = 0; q < 4; q++) {
            float u = uu[q];
            #pragma unroll
            for (int n = 0; n < 8; n++) {
                float nr = fmaf(ar[n], pr[n], u);
                nr = fmaf(-ai[n], pi[n], nr);
                float ni = ar[n] * pi[n];
                ni = fmaf(ai[n], pr[n], ni);
                pr[n] = nr; pi[n] = ni;
            }
        }
        u4 = nxt;
    }

    // m = a^256 (8 squarings)
    float mr[8], mi[8];
    #pragma unroll
    for (int n = 0; n < 8; n++) {
        float xr = ar[n], xi = ai[n];
        #pragma unroll
        for (int k = 0; k < 8; k++) {
            float nr = xr * xr - xi * xi;
            float ni = 2.f * xr * xi;
            xr = nr; xi = ni;
        }
        mr[n] = xr; mi[n] = xi;
    }

    // inclusive Hillis-Steele scan across 16 chunks (lane stride 4d keeps g fixed)
    #pragma unroll
    for (int d = 1; d < 16; d <<= 1) {
        #pragma unroll
        for (int n = 0; n < 8; n++) {
            float orr = __shfl_up(pr[n], (unsigned)(4 * d), 64);
            float oii = __shfl_up(pi[n], (unsigned)(4 * d), 64);
            float nr = fmaf(mr[n], orr, pr[n]);
            nr = fmaf(-mi[n], oii, nr);
            float ni = fmaf(mr[n], oii, pi[n]);
            ni = fmaf(mi[n], orr, ni);
            if (c >= d) { pr[n] = nr; pi[n] = ni; }
        }
        if (d < 8) {
            #pragma unroll
            for (int n = 0; n < 8; n++) {
                float nr = mr[n]*mr[n] - mi[n]*mi[n];
                float ni = 2.f*mr[n]*mi[n];
                mr[n] = nr; mi[n] = ni;
            }
        }
    }
    // exclusive: seed for chunk c = inclusive result of chunk c-1
    #pragma unroll
    for (int n = 0; n < 8; n++) {
        float sr_ = __shfl_up(pr[n], 4u, 64);
        float si_ = __shfl_up(pi[n], 4u, 64);
        pr[n] = (c >= 1) ? sr_ : 0.f;
        pi[n] = (c >= 1) ? si_ : 0.f;
    }

    // Ck = C*(a-1)/A
    float ckr[8], cki[8];
    #pragma unroll
    for (int n = 0; n < 8; n++) {
        float Are = -expf(log_A_real[pb + n]);
        float Aim = A_imag[pb + n];
        float inv = 1.f / (Are*Are + Aim*Aim);
        float numr = ar[n] - 1.f;
        float numi = ai[n];
        float tr = (numr*Are + numi*Aim) * inv;
        float ti = (numi*Are - numr*Aim) * inv;
        float cr = C_re[pb + n], ci = C_im[pb + n];
        ckr[n] = cr*tr - ci*ti;
        cki[n] = cr*ti + ci*tr;
    }

    float Dh = Dp[li * 256 + hh];
    ushort_t* gp = G + (size_t)bhl * 4096 + c * 256;

    // pass 2: seeded scan; partial dot per g-group, combined via shfl_xor(1,2);
    // lane g applies D-skip + gelu + store for step j+g.
    u4 = *(const float4*)(up);
    for (int j = 0; j < 256; j += 4) {
        float4 nxt;
        if (j + 4 < 256) nxt = *(const float4*)(up + j + 4);
        float uu[4] = {u4.x, u4.y, u4.z, u4.w};
        float ys[4];
        #pragma unroll
        for (int q = 0; q < 4; q++) {
            float u = uu[q];
            #pragma unroll
            for (int n = 0; n < 8; n++) {
                float nr = fmaf(ar[n], pr[n], u);
                nr = fmaf(-ai[n], pi[n], nr);
                float ni = ar[n] * pi[n];
                ni = fmaf(ai[n], pr[n], ni);
                pr[n] = nr; pi[n] = ni;
            }
            float y0 = 0.f, y1 = 0.f;
            #pragma unroll
            for (int n = 0; n < 8; n += 2) {
                y0 = fmaf(ckr[n],   pr[n],   y0); y0 = fmaf(-cki[n],   pi[n],   y0);
                y1 = fmaf(ckr[n+1], pr[n+1], y1); y1 = fmaf(-cki[n+1], pi[n+1], y1);
            }
            ys[q] = y0 + y1;
        }
        #pragma unroll
        for (int q = 0; q < 4; q++) {
            float yq = ys[q];
            yq += __shfl_xor(yq, 1, 64);
            yq += __shfl_xor(yq, 2, 64);
            ys[q] = yq;
        }
        float v = fmaf(Dh, uu[g], 2.f * ys[g]);
        float gv = v * 0.5f * (1.f + erff(v * 0.70710678118654752f));  // exact gelu
        gp[j + g] = f2bf(gv);
        u4 = nxt;
    }
}

// ---------------- GLU via bf16 MFMA: z = (Wa.y+ba) * sigmoid(Wg.y+bg), Hb += z ----------
// Block = 256 thr (4 waves), p-tile = 64 positions (one b), M = all 512 rows of W.
// Wave w owns a-channels [64w,64w+64) and g-channels [256+64w, ...): sigmoid pairing in-wave.
// G tile is register-transposed into LDS [p][k] (k padded 256->268).
#define LDK 268
__global__ __launch_bounds__(256, 2) void glu_kernel(
    const ushort_t* __restrict__ G, const ushort_t* __restrict__ wTb,
    const float* __restrict__ glu_b, float* __restrict__ Hb, int li, int b0)
{
    __shared__ ushort_t yt[64 * LDK];             // 34,304 B
    int t = threadIdx.x;
    int pf = blockIdx.x * 64;
    int bloc = pf >> 12;                          // batch local to G chunk
    int l0 = pf & 4095;
    int b = b0 + bloc;

    const ushort_t* gb = G + (size_t)bloc * 1048576 + l0;
    unsigned int* dst = (unsigned int*)&yt[0];
    #pragma unroll
    for (int i = 0; i < 4; i++) {
        int flat = i * 256 + t;
        int hp = flat >> 3;                       // 0..127 (h pair)
        int pg = flat & 7;                        // 0..7 (p group of 8)
        int h0 = hp * 2;
        uint4 va = *(const uint4*)(gb + (size_t)h0 * 4096 + pg * 8);
        uint4 vb = *(const uint4*)(gb + (size_t)(h0 + 1) * 4096 + pg * 8);
        const ushort_t* ra = (const ushort_t*)&va;
        const ushort_t* rb = (const ushort_t*)&vb;
        #pragma unroll
        for (int j = 0; j < 8; j++) {
            unsigned int v = (unsigned int)ra[j] | ((unsigned int)rb[j] << 16);
            dst[(pg * 8 + j) * (LDK / 2) + hp] = v;   // yt[p][k=h0] as dword pair
        }
    }
    __syncthreads();

    int lane = t & 63, w = t >> 6;
    int ln15 = lane & 15, quad = lane >> 4;
    int oA = w * 64;
    const ushort_t* wA = wTb + li * 131072;

    f32x4 accA[4][4] = {};
    f32x4 accG[4][4] = {};

    for (int ks = 0; ks < 8; ks++) {
        int kk = ks * 32 + quad * 8;
        bf16x8 af[4], gf[4];
        #pragma unroll
        for (int mt = 0; mt < 4; mt++) {
            int oa = oA + mt * 16 + ln15;
            af[mt] = *(const bf16x8*)(wA + (size_t)oa * 256 + kk);
            gf[mt] = *(const bf16x8*)(wA + (size_t)(oa + 256) * 256 + kk);
        }
        bf16x8 bfr[4];
        #pragma unroll
        for (int nt = 0; nt < 4; nt++) {
            const us4* yp = (const us4*)&yt[(nt * 16 + ln15) * LDK + kk]; // 8B-aligned
            us4 lo = yp[0], hi = yp[1];
            bf16x8 v;
            v[0] = (short)lo.x; v[1] = (short)lo.y; v[2] = (short)lo.z; v[3] = (short)lo.w;
            v[4] = (short)hi.x; v[5] = (short)hi.y; v[6] = (short)hi.z; v[7] = (short)hi.w;
            bfr[nt] = v;
        }
        #pragma unroll
        for (int mt = 0; mt < 4; mt++)
            #pragma unroll
            for (int nt = 0; nt < 4; nt++) {
                accA[mt][nt] = __builtin_amdgcn_mfma_f32_16x16x32_bf16(af[mt], bfr[nt], accA[mt][nt], 0, 0, 0);
                accG[mt][nt] = __builtin_amdgcn_mfma_f32_16x16x32_bf16(gf[mt], bfr[nt], accG[mt][nt], 0, 0, 0);
            }
    }

    // epilogue: C/D layout (m89): col = lane&15 (p), row = quad*4 + r (o)
    #pragma unroll
    for (int mt = 0; mt < 4; mt++) {
        #pragma unroll
        for (int r = 0; r < 4; r++) {
            int o = oA + mt * 16 + quad * 4 + r;
            float ba = glu_b[li * 512 + o];
            float bg = glu_b[li * 512 + 256 + o];
            float* hrow = Hb + (size_t)b * 1048576 + (size_t)o * 4096 + l0 + ln15;
            #pragma unroll
            for (int nt = 0; nt < 4; nt++) {
                float a = accA[mt][nt][r] + ba;
                float g = accG[mt][nt][r] + bg;
                float z = a / (1.f + expf(-g));
                hrow[nt * 16] += z;
            }
        }
    }
}

// ---------------- LayerNorm over H, in place, single global read ----------------
// Block = 64 positions x 4 h-quarters. Thread (q,p) keeps its 64 h-values in regs.
__global__ __launch_bounds__(256) void ln_kernel(float* __restrict__ Hb,
    const float* __restrict__ ln_g, const float* __restrict__ ln_b, int li)
{
    __shared__ float sred[4][64], sqred[4][64];
    __shared__ float gs[256], bs[256];
    int t = threadIdx.x;
    int q = t >> 6, p = t & 63;
    int pos0 = blockIdx.x * 64;                   // 2048 blocks over B*L
    int b = pos0 >> 12, l0 = pos0 & 4095;
    float* base = Hb + (size_t)b * 1048576 + (size_t)q * 64 * 4096 + l0 + p;

    gs[t] = ln_g[li * 256 + t];
    bs[t] = ln_b[li * 256 + t];

    float v[64];
    float s = 0.f, sq = 0.f;
    #pragma unroll
    for (int j = 0; j < 64; j++) {
        v[j] = base[(size_t)j * 4096];
        s += v[j]; sq = fmaf(v[j], v[j], sq);
    }
    sred[q][p] = s; sqred[q][p] = sq;
    __syncthreads();
    float S  = (sred[0][p]  + sred[1][p])  + (sred[2][p]  + sred[3][p]);
    float SQ = (sqred[0][p] + sqred[1][p]) + (sqred[2][p] + sqred[3][p]);
    float mu = S * (1.f / 256.f);
    float var = SQ * (1.f / 256.f) - mu * mu;
    float r = rsqrtf(var + 1e-5f);
    #pragma unroll
    for (int j = 0; j < 64; j++) {
        int h = q * 64 + j;
        base[(size_t)j * 4096] = (v[j] - mu) * r * gs[h] + bs[h];
    }
}

// ---------------- decoder ----------------
__global__ __launch_bounds__(256) void dec1_kernel(const float* __restrict__ Hb,
    const float* __restrict__ w1, const float* __restrict__ b1, float* __restrict__ y1)
{
    int bh = blockIdx.x;
    const float* base = Hb + (size_t)bh * 4096;
    int t = threadIdx.x;
    float s = 0.f;
    for (int l = t; l < 4096; l += 256) s = fmaf(base[l], w1[l], s);
    #pragma unroll
    for (int d = 32; d > 0; d >>= 1) s += __shfl_xor(s, d, 64);
    __shared__ float red[4];
    if ((t & 63) == 0) red[t >> 6] = s;
    __syncthreads();
    if (t == 0) y1[bh] = red[0] + red[1] + red[2] + red[3] + b1[0];
}

__global__ __launch_bounds__(256) void dec2_kernel(const float* __restrict__ y1,
    const float* __restrict__ w2, const float* __restrict__ b2, float* __restrict__ out)
{
    int t = threadIdx.x;
    int b = blockIdx.x * 4 + (t >> 6);
    int lane = t & 63;
    float s = 0.f;
    #pragma unroll
    for (int k = 0; k < 4; k++) s = fmaf(y1[b * 256 + lane + k * 64], w2[lane + k * 64], s);
    #pragma unroll
    for (int d = 32; d > 0; d >>= 1) s += __shfl_xor(s, d, 64);
    if (lane == 0) out[b] = 1.f / (1.f + expf(-(s + b2[0])));
}

extern "C" void kernel_launch(void* const* d_in, const int* in_sizes, int n_in,
                              void* d_out, int out_size, void* d_ws, size_t ws_size,
                              hipStream_t stream)
{
    const float* x      = (const float*)d_in[0];
    const float* enc_w  = (const float*)d_in[1];
    const float* enc_b  = (const float*)d_in[2];
    const float* log_dt = (const float*)d_in[3];
    const float* lAr    = (const float*)d_in[4];
    const float* Aim    = (const float*)d_in[5];
    const float* Cre    = (const float*)d_in[6];
    const float* Cim    = (const float*)d_in[7];
    const float* Dp     = (const float*)d_in[8];
    const float* glu_w  = (const float*)d_in[9];
    const float* glu_b  = (const float*)d_in[10];
    const float* ln_g   = (const float*)d_in[11];
    const float* ln_b   = (const float*)d_in[12];
    const float* w1     = (const float*)d_in[13];
    const float* b1     = (const float*)d_in[14];
    const float* w2     = (const float*)d_in[15];
    const float* b2     = (const float*)d_in[16];

    float* ws = (float*)d_ws;
    float* Hb     = ws;
    ushort_t* wTb = (ushort_t*)(ws + WS_WT_OFF);
    float* y1     = ws + WS_Y1_OFF;
    ushort_t* Gb  = (ushort_t*)(ws + WS_GB_OFF);
    float* outp   = (float*)d_out;

    // Pick G chunk size (batches) from actual ws_size; deterministic per call.
    size_t wsf = ws_size / 4;
    size_t avail_bf16 = (wsf > (size_t)WS_GB_OFF) ? (wsf - WS_GB_OFF) * 2 : 0;
    int nb = 32;
    while (nb > 1 && (size_t)nb * 1048576 > avail_bf16) nb >>= 1;

    wtb_kernel<<<2048, 256, 0, stream>>>(glu_w, wTb);
    enc_kernel<<<32768, 256, 0, stream>>>(x, enc_w, enc_b, Hb);
    for (int li = 0; li < 4; li++) {
        for (int b0 = 0; b0 < 32; b0 += nb) {
            s4d_kernel<<<nb * 64, 256, 0, stream>>>(Hb, Gb, log_dt, lAr, Aim, Cre, Cim,
                                                    Dp, li, b0 * 256);
            glu_kernel<<<nb * 64, 256, 0, stream>>>(Gb, wTb, glu_b, Hb, li, b0);
        }
        ln_kernel<<<2048, 256, 0, stream>>>(Hb, ln_g, ln_b, li);
    }
    dec1_kernel<<<8192, 256, 0, stream>>>(Hb, w1, b1, y1);
    dec2_kernel<<<8, 256, 0, stream>>>(y1, w2, b2, outp);
}

// Round 6
// 1535.330 us; speedup vs baseline: 2.5293x; 1.2612x over previous
//
#include <hip/hip_runtime.h>
#include <math.h>

// Problem constants: B=32, L=4096, CH=1, H=256, NL=4, N2=32
// Chunked-linear S4D: per (layer,h) the 256-step chunk response is linear:
//   y_local = T_h u  (T[l][j]=k[l-j], k[d]=2Re(Sum Ck a^d))
//   S_end   = V_h u  (V rows = Re/Im(a^{255-j}))
//   y_corr  = W_h seed (W[l][2s]=2Re(Ck a^{l+1}), W[l][2s+1]=-2Im(Ck a^{l+1}))
// seeds from a 16-chunk serial scan (P_c = a^256 P_{c-1} + S_c; seed_c = P_{c-1}).
// ws layout (float units):
#define WS_WT   33554432   // wTb bf16 (NL,512,256): 262,144 f
#define WS_Y1   33816576   // y1 fp32: 8,192 f
#define WS_A256 33824768   // a256 fp32 [256h][32s][2]: 16,384 f
#define WS_V    33841152   // V bf16 [256h][64][256]: 2,097,152 f
#define WS_ABUF 35938304   // A=[T|W] bf16 [256h][256][320]: 10,485,760 f
#define WS_S    46424064   // S/seed bf16 [256h][nb*16][64]: nb*131,072 f; then Gb
// high-water nb=16: 46,424,064 + 16*655,360 = 56,909,824 f = 227.6 MB

typedef unsigned short ushort_t;
struct __attribute__((aligned(8))) us4 { ushort_t x, y, z, w; };
typedef short bf16x8 __attribute__((ext_vector_type(8)));
typedef float f32x4  __attribute__((ext_vector_type(4)));

__device__ __forceinline__ float bf2f(ushort_t u) {
    union { unsigned int i; float f; } c; c.i = ((unsigned int)u) << 16; return c.f;
}
__device__ __forceinline__ ushort_t f2bf(float f) {
    union { float f; unsigned int i; } c; c.f = f;
    unsigned int x = c.i;
    unsigned int r = (x + 0x7FFF + ((x >> 16) & 1)) >> 16;   // RNE
    return (ushort_t)r;
}

// ---------------- encoder ----------------
__global__ __launch_bounds__(256) void enc_kernel(const float* __restrict__ x,
    const float* __restrict__ ew, const float* __restrict__ eb, float* __restrict__ Hb)
{
    int i = blockIdx.x * 256 + threadIdx.x;      // float4 units, 8,388,608 total
    int l4 = i & 1023;
    int h  = (i >> 10) & 255;
    int b  = i >> 18;
    float4 xv = *(const float4*)(x + (b << 12) + (l4 << 2));
    float w = ew[h], bb = eb[h];
    float4 o;
    o.x = fmaf(xv.x, w, bb); o.y = fmaf(xv.y, w, bb);
    o.z = fmaf(xv.z, w, bb); o.w = fmaf(xv.w, w, bb);
    *(float4*)(Hb + ((size_t)i << 2)) = o;
}

// ---------------- weight cast ----------------
__global__ __launch_bounds__(256) void wtb_kernel(const float* __restrict__ gw, ushort_t* __restrict__ wTb)
{
    int i = blockIdx.x * 256 + threadIdx.x;      // 524,288
    wTb[i] = f2bf(gw[i]);
}

// ---------------- prep: build A=[T|W], V, a256 for one layer ----------------
// grid 256 (h), block 256. Thread d: binary-exp a^d and a^(255-d) from LDS power table.
__global__ __launch_bounds__(256) void prep_kernel(
    const float* __restrict__ log_dt, const float* __restrict__ lAr,
    const float* __restrict__ Aim_, const float* __restrict__ Cre,
    const float* __restrict__ Cim, ushort_t* __restrict__ Abuf,
    ushort_t* __restrict__ Vg, float* __restrict__ a256tab, int li)
{
    __shared__ float s_ar[32], s_ai[32], s_ckr[32], s_cki[32];
    __shared__ float powr[8][32], powi[8][32];
    __shared__ float karr[256];
    __shared__ ushort_t Vt[256][66];              // padded 64->66
    int t = threadIdx.x;
    int h = blockIdx.x;
    int pb = (li * 256 + h) * 32;

    if (t < 32) {
        int s = t;
        float dt = expf(log_dt[li * 256 + h]);
        float Are = -expf(lAr[pb + s]);
        float Ai  = Aim_[pb + s];
        float e = expf(Are * dt);
        float ar = e * cosf(Ai * dt), ai = e * sinf(Ai * dt);
        float inv = 1.f / (Are * Are + Ai * Ai);
        float numr = ar - 1.f, numi = ai;
        float tr = (numr * Are + numi * Ai) * inv;
        float ti = (numi * Are - numr * Ai) * inv;
        float cr = Cre[pb + s], ci = Cim[pb + s];
        s_ar[s] = ar; s_ai[s] = ai;
        s_ckr[s] = 2.f * (cr * tr - ci * ti);     // ck2 = 2*Ck
        s_cki[s] = 2.f * (cr * ti + ci * tr);
        float xr = ar, xi = ai;
        for (int k = 0; k < 8; k++) {
            powr[k][s] = xr; powi[k][s] = xi;     // a^(2^k)
            float nr = xr * xr - xi * xi;
            float ni = 2.f * xr * xi;
            xr = nr; xi = ni;
        }
        a256tab[h * 64 + s * 2] = xr;             // a^256
        a256tab[h * 64 + s * 2 + 1] = xi;
    }
    __syncthreads();

    int d = t;
    // a^d
    float adr[32], adi[32];
    #pragma unroll
    for (int s = 0; s < 32; s++) { adr[s] = 1.f; adi[s] = 0.f; }
    #pragma unroll
    for (int bit = 0; bit < 8; bit++) {
        if (d & (1 << bit)) {
            #pragma unroll
            for (int s = 0; s < 32; s++) {
                float pr_ = powr[bit][s], pi_ = powi[bit][s];
                float nr = adr[s] * pr_ - adi[s] * pi_;
                float ni = adr[s] * pi_ + adi[s] * pr_;
                adr[s] = nr; adi[s] = ni;
            }
        }
    }
    // k[d] = Re(sum ck2 * a^d)
    float kd = 0.f;
    #pragma unroll
    for (int s = 0; s < 32; s++) kd += s_ckr[s] * adr[s] - s_cki[s] * adi[s];
    karr[d] = kd;
    // W row d: w = a^(d+1) = a^d * a;  cols 256+2s / 256+2s+1
    unsigned int wrow[32];
    #pragma unroll
    for (int s = 0; s < 32; s++) {
        float wr = adr[s] * s_ar[s] - adi[s] * s_ai[s];
        float wi = adr[s] * s_ai[s] + adi[s] * s_ar[s];
        float v0 = s_ckr[s] * wr - s_cki[s] * wi;       // Re(ck2*w)
        float v1 = -(s_ckr[s] * wi + s_cki[s] * wr);    // -Im(ck2*w)
        wrow[s] = (unsigned int)f2bf(v0) | ((unsigned int)f2bf(v1) << 16);
    }
    {
        ushort_t* arow = Abuf + (size_t)h * 81920 + (size_t)d * 320 + 256;
        #pragma unroll
        for (int q = 0; q < 8; q++) {
            uint4 v; v.x = wrow[q*4]; v.y = wrow[q*4+1]; v.z = wrow[q*4+2]; v.w = wrow[q*4+3];
            *(uint4*)(arow + q * 8) = v;
        }
    }
    // a^(255-d) -> Vt
    {
        int e = 255 - d;
        float evr[32], evi[32];
        #pragma unroll
        for (int s = 0; s < 32; s++) { evr[s] = 1.f; evi[s] = 0.f; }
        #pragma unroll
        for (int bit = 0; bit < 8; bit++) {
            if (e & (1 << bit)) {
                #pragma unroll
                for (int s = 0; s < 32; s++) {
                    float pr_ = powr[bit][s], pi_ = powi[bit][s];
                    float nr = evr[s] * pr_ - evi[s] * pi_;
                    float ni = evr[s] * pi_ + evi[s] * pr_;
                    evr[s] = nr; evi[s] = ni;
                }
            }
        }
        #pragma unroll
        for (int s = 0; s < 32; s++) {
            Vt[d][2*s]   = f2bf(evr[s]);
            Vt[d][2*s+1] = f2bf(evi[s]);
        }
    }
    __syncthreads();

    // T row l=t: T[l][j] = k[l-j] (j<=l), else 0
    {
        ushort_t* trow = Abuf + (size_t)h * 81920 + (size_t)t * 320;
        for (int j4 = 0; j4 < 64; j4++) {
            int j = j4 * 4;
            us4 v;
            v.x = (j     <= t) ? f2bf(karr[t - j    ]) : (ushort_t)0;
            v.y = (j + 1 <= t) ? f2bf(karr[t - j - 1]) : (ushort_t)0;
            v.z = (j + 2 <= t) ? f2bf(karr[t - j - 2]) : (ushort_t)0;
            v.w = (j + 3 <= t) ? f2bf(karr[t - j - 3]) : (ushort_t)0;
            *(us4*)(trow + j) = v;
        }
    }
    // V out: row m = t>>2, j-quarter = t&3 ; V[h][m][j]
    {
        int m = t >> 2, jq = t & 3;
        ushort_t* vrow = Vg + (size_t)h * 16384 + (size_t)m * 256 + jq * 64;
        for (int j4 = 0; j4 < 16; j4++) {
            int j = jq * 64 + j4 * 4;
            us4 v;
            v.x = Vt[j][m]; v.y = Vt[j+1][m]; v.z = Vt[j+2][m]; v.w = Vt[j+3][m];
            *(us4*)(vrow + j4 * 4) = v;
        }
    }
}

// ---------------- V-GEMM: S[h][n][m] = V_h (64x256) . u (256 x 64n-tile), bf16 out ----
__global__ __launch_bounds__(256, 2) void vgemm_kernel(
    const float* __restrict__ U, const ushort_t* __restrict__ Vg,
    ushort_t* __restrict__ Sb, int b0, int ntot)
{
    __shared__ ushort_t yt[64 * 264];             // [n][k], k padded 256->264
    int t = threadIdx.x;
    int h = blockIdx.x;
    int tile = blockIdx.y;
    int nl = t & 63, kq = t >> 6;
    int n = tile * 64 + nl;
    const float* ub = U + (size_t)(b0 + (n >> 4)) * 1048576 + (size_t)h * 4096 + (n & 15) * 256;
    #pragma unroll
    for (int i = 0; i < 16; i++) {
        int k = kq * 64 + i * 4;
        float4 u4 = *(const float4*)(ub + k);
        us4 v; v.x = f2bf(u4.x); v.y = f2bf(u4.y); v.z = f2bf(u4.z); v.w = f2bf(u4.w);
        *(us4*)(&yt[nl * 264 + k]) = v;
    }
    __syncthreads();

    int lane = t & 63, w = t >> 6;
    int ln15 = lane & 15, quad = lane >> 4;
    const ushort_t* va = Vg + (size_t)h * 16384 + (size_t)(w * 16 + ln15) * 256;
    f32x4 acc[4] = {};
    for (int ks = 0; ks < 8; ks++) {
        int kk = ks * 32 + quad * 8;
        bf16x8 af = *(const bf16x8*)(va + kk);
        #pragma unroll
        for (int nt = 0; nt < 4; nt++) {
            bf16x8 bf_ = *(const bf16x8*)(&yt[(nt * 16 + ln15) * 264 + kk]);
            acc[nt] = __builtin_amdgcn_mfma_f32_16x16x32_bf16(af, bf_, acc[nt], 0, 0, 0);
        }
    }
    #pragma unroll
    for (int nt = 0; nt < 4; nt++) {
        int nn = tile * 64 + nt * 16 + ln15;
        ushort_t* sp = Sb + ((size_t)h * ntot + nn) * 64 + w * 16 + quad * 4;
        us4 v;
        v.x = f2bf(acc[nt][0]); v.y = f2bf(acc[nt][1]);
        v.z = f2bf(acc[nt][2]); v.w = f2bf(acc[nt][3]);
        *(us4*)sp = v;
    }
}

// ---------------- seed scan: P_c = a256 P_{c-1} + S_c; write seed_c = P_{c-1} in place ---
__global__ __launch_bounds__(256) void scan_kernel(
    ushort_t* __restrict__ Sb, const float* __restrict__ a256tab, int ntot)
{
    int t = threadIdx.x;
    int lane = t & 63;
    int w = t >> 6;
    int sub = lane >> 5, s = lane & 31;
    int r = blockIdx.x * 8 + w * 2 + sub;         // row over nb*256 (b_local, h)
    int h = r & 255, bl = r >> 8;
    float m2r = a256tab[h * 64 + s * 2], m2i = a256tab[h * 64 + s * 2 + 1];
    float sr = 0.f, si = 0.f;
    for (int c = 0; c < 16; c++) {
        unsigned int* p = (unsigned int*)Sb + ((size_t)h * ntot + bl * 16 + c) * 32 + s;
        unsigned int sv = *p;
        float Sr = bf2f((ushort_t)(sv & 0xFFFF));
        float Si = bf2f((ushort_t)(sv >> 16));
        *p = (unsigned int)f2bf(sr) | ((unsigned int)f2bf(si) << 16);
        float nsr = m2r * sr - m2i * si + Sr;
        float nsi = m2r * si + m2i * sr + Si;
        sr = nsr; si = nsi;
    }
}

// ---------------- main GEMM: y = [T|W].[u;seed], + D*u, exact GELU, -> G bf16 ----------
__global__ __launch_bounds__(256, 2) void dgemm_kernel(
    const float* __restrict__ U, const ushort_t* __restrict__ Abuf,
    const ushort_t* __restrict__ Sb, const float* __restrict__ Dp,
    ushort_t* __restrict__ G, int li, int b0, int ntot)
{
    __shared__ ushort_t yt[64 * 328];             // [n][k], K=320 padded ->328
    int t = threadIdx.x;
    int h = blockIdx.x;
    int tile = blockIdx.y;
    int nl = t & 63, kq = t >> 6;
    int n = tile * 64 + nl;
    const float* ub = U + (size_t)(b0 + (n >> 4)) * 1048576 + (size_t)h * 4096 + (n & 15) * 256;
    #pragma unroll
    for (int i = 0; i < 16; i++) {
        int k = kq * 64 + i * 4;
        float4 u4 = *(const float4*)(ub + k);
        us4 v; v.x = f2bf(u4.x); v.y = f2bf(u4.y); v.z = f2bf(u4.z); v.w = f2bf(u4.w);
        *(us4*)(&yt[nl * 328 + k]) = v;
    }
    {   // seed rows: 16 us per kq
        const uint4* sp = (const uint4*)(Sb + ((size_t)h * ntot + n) * 64 + kq * 16);
        uint4 s0 = sp[0], s1 = sp[1];
        *(uint4*)(&yt[nl * 328 + 256 + kq * 16]) = s0;
        *(uint4*)(&yt[nl * 328 + 256 + kq * 16 + 8]) = s1;
    }
    __syncthreads();

    int lane = t & 63, w = t >> 6;
    int ln15 = lane & 15, quad = lane >> 4;
    const ushort_t* Ah = Abuf + (size_t)h * 81920;
    f32x4 acc[4][4] = {};
    for (int ks = 0; ks < 10; ks++) {
        int kk = ks * 32 + quad * 8;
        bf16x8 af[4];
        #pragma unroll
        for (int mt = 0; mt < 4; mt++)
            af[mt] = *(const bf16x8*)(Ah + (size_t)(w * 64 + mt * 16 + ln15) * 320 + kk);
        #pragma unroll
        for (int nt = 0; nt < 4; nt++) {
            bf16x8 bf_ = *(const bf16x8*)(&yt[(nt * 16 + ln15) * 328 + kk]);
            #pragma unroll
            for (int mt = 0; mt < 4; mt++)
                acc[mt][nt] = __builtin_amdgcn_mfma_f32_16x16x32_bf16(af[mt], bf_, acc[mt][nt], 0, 0, 0);
        }
    }
    float Dh = Dp[li * 256 + h];
    #pragma unroll
    for (int mt = 0; mt < 4; mt++) {
        #pragma unroll
        for (int nt = 0; nt < 4; nt++) {
            int nn = tile * 64 + nt * 16 + ln15;
            int lb = w * 64 + mt * 16 + quad * 4;
            us4 uv = *(const us4*)(&yt[(nt * 16 + ln15) * 328 + lb]);
            float uu[4] = {bf2f(uv.x), bf2f(uv.y), bf2f(uv.z), bf2f(uv.w)};
            us4 o;
            ushort_t* op = &o.x;
            #pragma unroll
            for (int rr = 0; rr < 4; rr++) {
                float v = acc[mt][nt][rr] + Dh * uu[rr];
                float g = v * 0.5f * (1.f + erff(v * 0.70710678118654752f));
                op[rr] = f2bf(g);
            }
            ushort_t* gp = G + ((size_t)(nn >> 4) * 256 + h) * 4096 + (nn & 15) * 256 + lb;
            *(us4*)gp = o;
        }
    }
}

// ---------------- GLU via bf16 MFMA (unchanged from R5) ----------------
#define LDK 268
__global__ __launch_bounds__(256, 2) void glu_kernel(
    const ushort_t* __restrict__ G, const ushort_t* __restrict__ wTb,
    const float* __restrict__ glu_b, float* __restrict__ Hb, int li, int b0)
{
    __shared__ ushort_t yt[64 * LDK];
    int t = threadIdx.x;
    int pf = blockIdx.x * 64;
    int bloc = pf >> 12;
    int l0 = pf & 4095;
    int b = b0 + bloc;

    const ushort_t* gb = G + (size_t)bloc * 1048576 + l0;
    unsigned int* dst = (unsigned int*)&yt[0];
    #pragma unroll
    for (int i = 0; i < 4; i++) {
        int flat = i * 256 + t;
        int hp = flat >> 3;
        int pg = flat & 7;
        int h0 = hp * 2;
        uint4 va = *(const uint4*)(gb + (size_t)h0 * 4096 + pg * 8);
        uint4 vb = *(const uint4*)(gb + (size_t)(h0 + 1) * 4096 + pg * 8);
        const ushort_t* ra = (const ushort_t*)&va;
        const ushort_t* rb = (const ushort_t*)&vb;
        #pragma unroll
        for (int j = 0; j < 8; j++) {
            unsigned int v = (unsigned int)ra[j] | ((unsigned int)rb[j] << 16);
            dst[(pg * 8 + j) * (LDK / 2) + hp] = v;
        }
    }
    __syncthreads();

    int lane = t & 63, w = t >> 6;
    int ln15 = lane & 15, quad = lane >> 4;
    int oA = w * 64;
    const ushort_t* wA = wTb + li * 131072;

    f32x4 accA[4][4] = {};
    f32x4 accG[4][4] = {};

    for (int ks = 0; ks < 8; ks++) {
        int kk = ks * 32 + quad * 8;
        bf16x8 af[4], gf[4];
        #pragma unroll
        for (int mt = 0; mt < 4; mt++) {
            int oa = oA + mt * 16 + ln15;
            af[mt] = *(const bf16x8*)(wA + (size_t)oa * 256 + kk);
            gf[mt] = *(const bf16x8*)(wA + (size_t)(oa + 256) * 256 + kk);
        }
        bf16x8 bfr[4];
        #pragma unroll
        for (int nt = 0; nt < 4; nt++) {
            const us4* yp = (const us4*)&yt[(nt * 16 + ln15) * LDK + kk];
            us4 lo = yp[0], hi = yp[1];
            bf16x8 v;
            v[0] = (short)lo.x; v[1] = (short)lo.y; v[2] = (short)lo.z; v[3] = (short)lo.w;
            v[4] = (short)hi.x; v[5] = (short)hi.y; v[6] = (short)hi.z; v[7] = (short)hi.w;
            bfr[nt] = v;
        }
        #pragma unroll
        for (int mt = 0; mt < 4; mt++)
            #pragma unroll
            for (int nt = 0; nt < 4; nt++) {
                accA[mt][nt] = __builtin_amdgcn_mfma_f32_16x16x32_bf16(af[mt], bfr[nt], accA[mt][nt], 0, 0, 0);
                accG[mt][nt] = __builtin_amdgcn_mfma_f32_16x16x32_bf16(gf[mt], bfr[nt], accG[mt][nt], 0, 0, 0);
            }
    }

    #pragma unroll
    for (int mt = 0; mt < 4; mt++) {
        #pragma unroll
        for (int r = 0; r < 4; r++) {
            int o = oA + mt * 16 + quad * 4 + r;
            float ba = glu_b[li * 512 + o];
            float bg = glu_b[li * 512 + 256 + o];
            float* hrow = Hb + (size_t)b * 1048576 + (size_t)o * 4096 + l0 + ln15;
            #pragma unroll
            for (int nt = 0; nt < 4; nt++) {
                float a = accA[mt][nt][r] + ba;
                float g = accG[mt][nt][r] + bg;
                float z = a / (1.f + expf(-g));
                hrow[nt * 16] += z;
            }
        }
    }
}

// ---------------- LayerNorm (unchanged from R5) ----------------
__global__ __launch_bounds__(256) void ln_kernel(float* __restrict__ Hb,
    const float* __restrict__ ln_g, const float* __restrict__ ln_b, int li)
{
    __shared__ float sred[4][64], sqred[4][64];
    __shared__ float gs[256], bs[256];
    int t = threadIdx.x;
    int q = t >> 6, p = t & 63;
    int pos0 = blockIdx.x * 64;
    int b = pos0 >> 12, l0 = pos0 & 4095;
    float* base = Hb + (size_t)b * 1048576 + (size_t)q * 64 * 4096 + l0 + p;

    gs[t] = ln_g[li * 256 + t];
    bs[t] = ln_b[li * 256 + t];

    float v[64];
    float s = 0.f, sq = 0.f;
    #pragma unroll
    for (int j = 0; j < 64; j++) {
        v[j] = base[(size_t)j * 4096];
        s += v[j]; sq = fmaf(v[j], v[j], sq);
    }
    sred[q][p] = s; sqred[q][p] = sq;
    __syncthreads();
    float S  = (sred[0][p]  + sred[1][p])  + (sred[2][p]  + sred[3][p]);
    float SQ = (sqred[0][p] + sqred[1][p]) + (sqred[2][p] + sqred[3][p]);
    float mu = S * (1.f / 256.f);
    float var = SQ * (1.f / 256.f) - mu * mu;
    float r = rsqrtf(var + 1e-5f);
    #pragma unroll
    for (int j = 0; j < 64; j++) {
        int h = q * 64 + j;
        base[(size_t)j * 4096] = (v[j] - mu) * r * gs[h] + bs[h];
    }
}

// ---------------- decoder ----------------
__global__ __launch_bounds__(256) void dec1_kernel(const float* __restrict__ Hb,
    const float* __restrict__ w1, const float* __restrict__ b1, float* __restrict__ y1)
{
    int bh = blockIdx.x;
    const float* base = Hb + (size_t)bh * 4096;
    int t = threadIdx.x;
    float s = 0.f;
    for (int l = t; l < 4096; l += 256) s = fmaf(base[l], w1[l], s);
    #pragma unroll
    for (int d = 32; d > 0; d >>= 1) s += __shfl_xor(s, d, 64);
    __shared__ float red[4];
    if ((t & 63) == 0) red[t >> 6] = s;
    __syncthreads();
    if (t == 0) y1[bh] = red[0] + red[1] + red[2] + red[3] + b1[0];
}

__global__ __launch_bounds__(256) void dec2_kernel(const float* __restrict__ y1,
    const float* __restrict__ w2, const float* __restrict__ b2, float* __restrict__ out)
{
    int t = threadIdx.x;
    int b = blockIdx.x * 4 + (t >> 6);
    int lane = t & 63;
    float s = 0.f;
    #pragma unroll
    for (int k = 0; k < 4; k++) s = fmaf(y1[b * 256 + lane + k * 64], w2[lane + k * 64], s);
    #pragma unroll
    for (int d = 32; d > 0; d >>= 1) s += __shfl_xor(s, d, 64);
    if (lane == 0) out[b] = 1.f / (1.f + expf(-(s + b2[0])));
}

extern "C" void kernel_launch(void* const* d_in, const int* in_sizes, int n_in,
                              void* d_out, int out_size, void* d_ws, size_t ws_size,
                              hipStream_t stream)
{
    const float* x      = (const float*)d_in[0];
    const float* enc_w  = (const float*)d_in[1];
    const float* enc_b  = (const float*)d_in[2];
    const float* log_dt = (const float*)d_in[3];
    const float* lAr    = (const float*)d_in[4];
    const float* Aim    = (const float*)d_in[5];
    const float* Cre    = (const float*)d_in[6];
    const float* Cim    = (const float*)d_in[7];
    const float* Dp     = (const float*)d_in[8];
    const float* glu_w  = (const float*)d_in[9];
    const float* glu_b  = (const float*)d_in[10];
    const float* ln_g   = (const float*)d_in[11];
    const float* ln_b   = (const float*)d_in[12];
    const float* w1     = (const float*)d_in[13];
    const float* b1     = (const float*)d_in[14];
    const float* w2     = (const float*)d_in[15];
    const float* b2     = (const float*)d_in[16];

    float* ws = (float*)d_ws;
    float* Hb      = ws;
    ushort_t* wTb  = (ushort_t*)(ws + WS_WT);
    float* y1      = ws + WS_Y1;
    float* a256    = ws + WS_A256;
    ushort_t* Vg   = (ushort_t*)(ws + WS_V);
    ushort_t* Abuf = (ushort_t*)(ws + WS_ABUF);
    float* outp    = (float*)d_out;

    size_t wsf = ws_size / 4;
    int nb = 16;
    while (nb > 4 && (size_t)WS_S + (size_t)nb * 655360 > wsf) nb >>= 1;
    int ntot = nb * 16;
    ushort_t* Sb = (ushort_t*)(ws + WS_S);
    ushort_t* Gb = (ushort_t*)(ws + WS_S + (size_t)nb * 131072);

    wtb_kernel<<<2048, 256, 0, stream>>>(glu_w, wTb);
    enc_kernel<<<32768, 256, 0, stream>>>(x, enc_w, enc_b, Hb);
    for (int li = 0; li < 4; li++) {
        prep_kernel<<<256, 256, 0, stream>>>(log_dt, lAr, Aim, Cre, Cim, Abuf, Vg, a256, li);
        for (int b0 = 0; b0 < 32; b0 += nb) {
            vgemm_kernel<<<dim3(256, nb / 4), 256, 0, stream>>>(Hb, Vg, Sb, b0, ntot);
            scan_kernel<<<nb * 32, 256, 0, stream>>>(Sb, a256, ntot);
            dgemm_kernel<<<dim3(256, nb / 4), 256, 0, stream>>>(Hb, Abuf, Sb, Dp, Gb, li, b0, ntot);
            glu_kernel<<<nb * 64, 256, 0, stream>>>(Gb, wTb, glu_b, Hb, li, b0);
        }
        ln_kernel<<<2048, 256, 0, stream>>>(Hb, ln_g, ln_b, li);
    }
    dec1_kernel<<<8192, 256, 0, stream>>>(Hb, w1, b1, y1);
    dec2_kernel<<<8, 256, 0, stream>>>(y1, w2, b2, outp);
}

// Round 8
// 1131.679 us; speedup vs baseline: 3.4315x; 1.3567x over previous
//
#include <hip/hip_runtime.h>
#include <math.h>

// Problem constants: B=32, L=4096, CH=1, H=256, NL=4, N2=32
// Residual stream Hbf is bf16 [b][h][l]. Chunked-linear S4D (see R6):
//   y = T_h u + W_h seed, S = V_h u, seeds via 16-chunk serial scan.
// ws layout (float units):
#define WS_WT   16777216   // wTb bf16 (NL,512,256): 262,144 f
#define WS_Y1   17039360   // y1 fp32: 8,192 f
#define WS_A256 17047552   // a256 fp32 [256h][32s][2]: 16,384 f
#define WS_V    17063936   // V bf16 [256h][64][256]: 2,097,152 f
#define WS_ABUF 19161088   // A=[T|W] bf16 [256h][256][320]: 10,485,760 f
#define WS_S    29646848   // S bf16 [256h][ntot][64]: nb*131,072 f; then Gb nb*524,288 f
// high-water nb=32: 29,646,848 + 32*655,360 = 50,618,368 f = 202.5 MB

typedef unsigned short ushort_t;
struct __attribute__((aligned(8))) us4 { ushort_t x, y, z, w; };
typedef short bf16x8 __attribute__((ext_vector_type(8)));
typedef float f32x4  __attribute__((ext_vector_type(4)));

__device__ __forceinline__ float bf2f(ushort_t u) {
    union { unsigned int i; float f; } c; c.i = ((unsigned int)u) << 16; return c.f;
}
__device__ __forceinline__ ushort_t f2bf(float f) {
    union { float f; unsigned int i; } c; c.f = f;
    unsigned int x = c.i;
    unsigned int r = (x + 0x7FFF + ((x >> 16) & 1)) >> 16;   // RNE
    return (ushort_t)r;
}

// ---------------- encoder: bf16 h[b][h][l] ----------------
__global__ __launch_bounds__(256) void enc_kernel(const float* __restrict__ x,
    const float* __restrict__ ew, const float* __restrict__ eb, ushort_t* __restrict__ Hb)
{
    int i = blockIdx.x * 256 + threadIdx.x;      // 8-us units, 4,194,304 total
    int l8 = i & 511;
    int h  = (i >> 9) & 255;
    int b  = i >> 17;
    const float* xp = x + ((size_t)b << 12) + (l8 << 3);
    float4 a0 = ((const float4*)xp)[0];
    float4 a1 = ((const float4*)xp)[1];
    float w = ew[h], bb = eb[h];
    us4 o0, o1;
    o0.x = f2bf(fmaf(a0.x, w, bb)); o0.y = f2bf(fmaf(a0.y, w, bb));
    o0.z = f2bf(fmaf(a0.z, w, bb)); o0.w = f2bf(fmaf(a0.w, w, bb));
    o1.x = f2bf(fmaf(a1.x, w, bb)); o1.y = f2bf(fmaf(a1.y, w, bb));
    o1.z = f2bf(fmaf(a1.z, w, bb)); o1.w = f2bf(fmaf(a1.w, w, bb));
    us4* op = (us4*)(Hb + ((size_t)i << 3));
    op[0] = o0; op[1] = o1;
}

// ---------------- weight cast ----------------
__global__ __launch_bounds__(256) void wtb_kernel(const float* __restrict__ gw, ushort_t* __restrict__ wTb)
{
    int i = blockIdx.x * 256 + threadIdx.x;      // 524,288
    wTb[i] = f2bf(gw[i]);
}

// ---------------- prep: build A=[T|W], V, a256 for one layer ----------------
__global__ __launch_bounds__(256) void prep_kernel(
    const float* __restrict__ log_dt, const float* __restrict__ lAr,
    const float* __restrict__ Aim_, const float* __restrict__ Cre,
    const float* __restrict__ Cim, ushort_t* __restrict__ Abuf,
    ushort_t* __restrict__ Vg, float* __restrict__ a256tab, int li)
{
    __shared__ float s_ar[32], s_ai[32], s_ckr[32], s_cki[32];
    __shared__ float powr[8][32], powi[8][32];
    __shared__ float karr[256];
    __shared__ ushort_t Vt[256][66];
    int t = threadIdx.x;
    int h = blockIdx.x;
    int pb = (li * 256 + h) * 32;

    if (t < 32) {
        int s = t;
        float dt = expf(log_dt[li * 256 + h]);
        float Are = -expf(lAr[pb + s]);
        float Ai  = Aim_[pb + s];
        float e = expf(Are * dt);
        float ar = e * cosf(Ai * dt), ai = e * sinf(Ai * dt);
        float inv = 1.f / (Are * Are + Ai * Ai);
        float numr = ar - 1.f, numi = ai;
        float tr = (numr * Are + numi * Ai) * inv;
        float ti = (numi * Are - numr * Ai) * inv;
        float cr = Cre[pb + s], ci = Cim[pb + s];
        s_ar[s] = ar; s_ai[s] = ai;
        s_ckr[s] = 2.f * (cr * tr - ci * ti);
        s_cki[s] = 2.f * (cr * ti + ci * tr);
        float xr = ar, xi = ai;
        for (int k = 0; k < 8; k++) {
            powr[k][s] = xr; powi[k][s] = xi;
            float nr = xr * xr - xi * xi;
            float ni = 2.f * xr * xi;
            xr = nr; xi = ni;
        }
        a256tab[h * 64 + s * 2] = xr;
        a256tab[h * 64 + s * 2 + 1] = xi;
    }
    __syncthreads();

    int d = t;
    float adr[32], adi[32];
    #pragma unroll
    for (int s = 0; s < 32; s++) { adr[s] = 1.f; adi[s] = 0.f; }
    #pragma unroll
    for (int bit = 0; bit < 8; bit++) {
        if (d & (1 << bit)) {
            #pragma unroll
            for (int s = 0; s < 32; s++) {
                float pr_ = powr[bit][s], pi_ = powi[bit][s];
                float nr = adr[s] * pr_ - adi[s] * pi_;
                float ni = adr[s] * pi_ + adi[s] * pr_;
                adr[s] = nr; adi[s] = ni;
            }
        }
    }
    float kd = 0.f;
    #pragma unroll
    for (int s = 0; s < 32; s++) kd += s_ckr[s] * adr[s] - s_cki[s] * adi[s];
    karr[d] = kd;
    unsigned int wrow[32];
    #pragma unroll
    for (int s = 0; s < 32; s++) {
        float wr = adr[s] * s_ar[s] - adi[s] * s_ai[s];
        float wi = adr[s] * s_ai[s] + adi[s] * s_ar[s];
        float v0 = s_ckr[s] * wr - s_cki[s] * wi;
        float v1 = -(s_ckr[s] * wi + s_cki[s] * wr);
        wrow[s] = (unsigned int)f2bf(v0) | ((unsigned int)f2bf(v1) << 16);
    }
    {
        ushort_t* arow = Abuf + (size_t)h * 81920 + (size_t)d * 320 + 256;
        #pragma unroll
        for (int q = 0; q < 8; q++) {
            uint4 v; v.x = wrow[q*4]; v.y = wrow[q*4+1]; v.z = wrow[q*4+2]; v.w = wrow[q*4+3];
            *(uint4*)(arow + q * 8) = v;
        }
    }
    {
        int e = 255 - d;
        float evr[32], evi[32];
        #pragma unroll
        for (int s = 0; s < 32; s++) { evr[s] = 1.f; evi[s] = 0.f; }
        #pragma unroll
        for (int bit = 0; bit < 8; bit++) {
            if (e & (1 << bit)) {
                #pragma unroll
                for (int s = 0; s < 32; s++) {
                    float pr_ = powr[bit][s], pi_ = powi[bit][s];
                    float nr = evr[s] * pr_ - evi[s] * pi_;
                    float ni = evr[s] * pi_ + evi[s] * pr_;
                    evr[s] = nr; evi[s] = ni;
                }
            }
        }
        #pragma unroll
        for (int s = 0; s < 32; s++) {
            Vt[d][2*s]   = f2bf(evr[s]);
            Vt[d][2*s+1] = f2bf(evi[s]);
        }
    }
    __syncthreads();

    {
        ushort_t* trow = Abuf + (size_t)h * 81920 + (size_t)t * 320;
        for (int j4 = 0; j4 < 64; j4++) {
            int j = j4 * 4;
            us4 v;
            v.x = (j     <= t) ? f2bf(karr[t - j    ]) : (ushort_t)0;
            v.y = (j + 1 <= t) ? f2bf(karr[t - j - 1]) : (ushort_t)0;
            v.z = (j + 2 <= t) ? f2bf(karr[t - j - 2]) : (ushort_t)0;
            v.w = (j + 3 <= t) ? f2bf(karr[t - j - 3]) : (ushort_t)0;
            *(us4*)(trow + j) = v;
        }
    }
    {
        int m = t >> 2, jq = t & 3;
        ushort_t* vrow = Vg + (size_t)h * 16384 + (size_t)m * 256 + jq * 64;
        for (int j4 = 0; j4 < 16; j4++) {
            int j = jq * 64 + j4 * 4;
            us4 v;
            v.x = Vt[j][m]; v.y = Vt[j+1][m]; v.z = Vt[j+2][m]; v.w = Vt[j+3][m];
            *(us4*)(vrow + j4 * 4) = v;
        }
    }
}

// ---------------- V-GEMM: S = V_h . u (bf16 input) ----------------
__global__ __launch_bounds__(256, 2) void vgemm_kernel(
    const ushort_t* __restrict__ U, const ushort_t* __restrict__ Vg,
    ushort_t* __restrict__ Sb, int b0, int ntot)
{
    __shared__ ushort_t yt[64 * 264];
    int t = threadIdx.x;
    int h = blockIdx.x;
    int tile = blockIdx.y;
    int nl = t & 63, kq = t >> 6;
    int n = tile * 64 + nl;
    const ushort_t* ub = U + (size_t)(b0 + (n >> 4)) * 1048576 + (size_t)h * 4096 + (n & 15) * 256;
    // uint4 = 8 ushorts -> 8 iterations of stride 8 cover the 64-us strip (R7 bug: stride 16)
    #pragma unroll
    for (int i = 0; i < 8; i++) {
        int k = kq * 64 + i * 8;
        *(uint4*)(&yt[nl * 264 + k]) = *(const uint4*)(ub + k);
    }
    __syncthreads();

    int lane = t & 63, w = t >> 6;
    int ln15 = lane & 15, quad = lane >> 4;
    const ushort_t* va = Vg + (size_t)h * 16384 + (size_t)(w * 16 + ln15) * 256;
    f32x4 acc[4] = {};
    for (int ks = 0; ks < 8; ks++) {
        int kk = ks * 32 + quad * 8;
        bf16x8 af = *(const bf16x8*)(va + kk);
        #pragma unroll
        for (int nt = 0; nt < 4; nt++) {
            bf16x8 bf_ = *(const bf16x8*)(&yt[(nt * 16 + ln15) * 264 + kk]);  // 264us=528B row: 16B-aligned
            acc[nt] = __builtin_amdgcn_mfma_f32_16x16x32_bf16(af, bf_, acc[nt], 0, 0, 0);
        }
    }
    #pragma unroll
    for (int nt = 0; nt < 4; nt++) {
        int nn = tile * 64 + nt * 16 + ln15;
        ushort_t* sp = Sb + ((size_t)h * ntot + nn) * 64 + w * 16 + quad * 4;
        us4 v;
        v.x = f2bf(acc[nt][0]); v.y = f2bf(acc[nt][1]);
        v.z = f2bf(acc[nt][2]); v.w = f2bf(acc[nt][3]);
        *(us4*)sp = v;
    }
}

// ---------------- seed scan ----------------
__global__ __launch_bounds__(256) void scan_kernel(
    ushort_t* __restrict__ Sb, const float* __restrict__ a256tab, int ntot)
{
    int t = threadIdx.x;
    int lane = t & 63;
    int w = t >> 6;
    int sub = lane >> 5, s = lane & 31;
    int r = blockIdx.x * 8 + w * 2 + sub;
    int h = r & 255, bl = r >> 8;
    float m2r = a256tab[h * 64 + s * 2], m2i = a256tab[h * 64 + s * 2 + 1];
    float sr = 0.f, si = 0.f;
    for (int c = 0; c < 16; c++) {
        unsigned int* p = (unsigned int*)Sb + ((size_t)h * ntot + bl * 16 + c) * 32 + s;
        unsigned int sv = *p;
        float Sr = bf2f((ushort_t)(sv & 0xFFFF));
        float Si = bf2f((ushort_t)(sv >> 16));
        *p = (unsigned int)f2bf(sr) | ((unsigned int)f2bf(si) << 16);
        float nsr = m2r * sr - m2i * si + Sr;
        float nsi = m2r * si + m2i * sr + Si;
        sr = nsr; si = nsi;
    }
}

// ---------------- main GEMM: y=[T|W].[u;seed], +D*u, GELU -> G bf16 ----------------
__global__ __launch_bounds__(256, 2) void dgemm_kernel(
    const ushort_t* __restrict__ U, const ushort_t* __restrict__ Abuf,
    const ushort_t* __restrict__ Sb, const float* __restrict__ Dp,
    ushort_t* __restrict__ G, int li, int b0, int ntot)
{
    __shared__ ushort_t yt[64 * 328];
    int t = threadIdx.x;
    int h = blockIdx.x;
    int tile = blockIdx.y;
    int nl = t & 63, kq = t >> 6;
    int n = tile * 64 + nl;
    const ushort_t* ub = U + (size_t)(b0 + (n >> 4)) * 1048576 + (size_t)h * 4096 + (n & 15) * 256;
    #pragma unroll
    for (int i = 0; i < 8; i++) {
        int k = kq * 64 + i * 8;                 // uint4 = 8 us (R7 bug: stride 16)
        *(uint4*)(&yt[nl * 328 + k]) = *(const uint4*)(ub + k);
    }
    {
        const uint4* sp = (const uint4*)(Sb + ((size_t)h * ntot + n) * 64 + kq * 16);
        *(uint4*)(&yt[nl * 328 + 256 + kq * 16]) = sp[0];
        *(uint4*)(&yt[nl * 328 + 256 + kq * 16 + 8]) = sp[1];
    }
    __syncthreads();

    int lane = t & 63, w = t >> 6;
    int ln15 = lane & 15, quad = lane >> 4;
    const ushort_t* Ah = Abuf + (size_t)h * 81920;
    f32x4 acc[4][4] = {};
    for (int ks = 0; ks < 10; ks++) {
        int kk = ks * 32 + quad * 8;
        bf16x8 af[4];
        #pragma unroll
        for (int mt = 0; mt < 4; mt++)
            af[mt] = *(const bf16x8*)(Ah + (size_t)(w * 64 + mt * 16 + ln15) * 320 + kk);
        #pragma unroll
        for (int nt = 0; nt < 4; nt++) {
            bf16x8 bf_ = *(const bf16x8*)(&yt[(nt * 16 + ln15) * 328 + kk]);  // 328us=656B row: 16B-aligned
            #pragma unroll
            for (int mt = 0; mt < 4; mt++)
                acc[mt][nt] = __builtin_amdgcn_mfma_f32_16x16x32_bf16(af[mt], bf_, acc[mt][nt], 0, 0, 0);
        }
    }
    float Dh = Dp[li * 256 + h];
    #pragma unroll
    for (int mt = 0; mt < 4; mt++) {
        #pragma unroll
        for (int nt = 0; nt < 4; nt++) {
            int nn = tile * 64 + nt * 16 + ln15;
            int lb = w * 64 + mt * 16 + quad * 4;
            us4 uv = *(const us4*)(&yt[(nt * 16 + ln15) * 328 + lb]);
            float uu[4] = {bf2f(uv.x), bf2f(uv.y), bf2f(uv.z), bf2f(uv.w)};
            us4 o;
            ushort_t* op = &o.x;
            #pragma unroll
            for (int rr = 0; rr < 4; rr++) {
                float v = acc[mt][nt][rr] + Dh * uu[rr];
                float g = v * 0.5f * (1.f + erff(v * 0.70710678118654752f));
                op[rr] = f2bf(g);
            }
            ushort_t* gp = G + ((size_t)(nn >> 4) * 256 + h) * 4096 + (nn & 15) * 256 + lb;
            *(us4*)gp = o;
        }
    }
}

// ---------------- GLU + residual + LayerNorm fused, bf16 residual stream -----------
#define LDK 268
__global__ __launch_bounds__(256, 2) void gluln_kernel(
    const ushort_t* __restrict__ G, const ushort_t* __restrict__ wTb,
    const float* __restrict__ glu_b, const float* __restrict__ ln_g,
    const float* __restrict__ ln_b, ushort_t* __restrict__ Hb, int li, int b0)
{
    __shared__ ushort_t yt[64 * LDK];
    __shared__ float redS[16][66], redQ[16][66];
    __shared__ float mup[64], rstd[64];
    int t = threadIdx.x;
    int pf = blockIdx.x * 64;
    int bloc = pf >> 12;
    int l0 = pf & 4095;
    int b = b0 + bloc;

    const ushort_t* gb = G + (size_t)bloc * 1048576 + l0;
    unsigned int* dst = (unsigned int*)&yt[0];
    #pragma unroll
    for (int i = 0; i < 4; i++) {
        int hp = ((i & 1) << 6) + (t >> 2);       // 0..127
        int pg = ((i >> 1) << 2) + (t & 3);       // 0..7
        int h0 = hp * 2;
        uint4 va = *(const uint4*)(gb + (size_t)h0 * 4096 + pg * 8);
        uint4 vb = *(const uint4*)(gb + (size_t)(h0 + 1) * 4096 + pg * 8);
        const ushort_t* ra = (const ushort_t*)&va;
        const ushort_t* rb = (const ushort_t*)&vb;
        #pragma unroll
        for (int j = 0; j < 8; j++) {
            unsigned int v = (unsigned int)ra[j] | ((unsigned int)rb[j] << 16);
            dst[(pg * 8 + j) * (LDK / 2) + hp] = v;
        }
    }
    __syncthreads();

    int lane = t & 63, w = t >> 6;
    int ln15 = lane & 15, quad = lane >> 4;
    int oA = w * 64;
    const ushort_t* wA = wTb + li * 131072;

    f32x4 accA[4][4] = {};
    f32x4 accG[4][4] = {};

    for (int ks = 0; ks < 8; ks++) {
        int kk = ks * 32 + quad * 8;
        bf16x8 af[4], gf[4];
        #pragma unroll
        for (int mt = 0; mt < 4; mt++) {
            int oa = oA + mt * 16 + ln15;
            af[mt] = *(const bf16x8*)(wA + (size_t)oa * 256 + kk);
            gf[mt] = *(const bf16x8*)(wA + (size_t)(oa + 256) * 256 + kk);
        }
        bf16x8 bfr[4];
        #pragma unroll
        for (int nt = 0; nt < 4; nt++) {
            // LDK row stride = 536B (8B-aligned only): must load as two 8B us4, not one 16B bf16x8
            const us4* yp = (const us4*)&yt[(nt * 16 + ln15) * LDK + kk];
            us4 lo = yp[0], hi = yp[1];
            bf16x8 v;
            v[0] = (short)lo.x; v[1] = (short)lo.y; v[2] = (short)lo.z; v[3] = (short)lo.w;
            v[4] = (short)hi.x; v[5] = (short)hi.y; v[6] = (short)hi.z; v[7] = (short)hi.w;
            bfr[nt] = v;
        }
        #pragma unroll
        for (int mt = 0; mt < 4; mt++)
            #pragma unroll
            for (int nt = 0; nt < 4; nt++) {
                accA[mt][nt] = __builtin_amdgcn_mfma_f32_16x16x32_bf16(af[mt], bfr[nt], accA[mt][nt], 0, 0, 0);
                accG[mt][nt] = __builtin_amdgcn_mfma_f32_16x16x32_bf16(gf[mt], bfr[nt], accG[mt][nt], 0, 0, 0);
            }
    }

    // epilogue: z = (a+ba)*sigmoid(g+bg); hn = z + h_old; LN over 256 ch; store bf16
    ushort_t* hb_ = Hb + (size_t)b * 1048576;
    float ps[4] = {0.f, 0.f, 0.f, 0.f}, pq[4] = {0.f, 0.f, 0.f, 0.f};
    #pragma unroll
    for (int mt = 0; mt < 4; mt++) {
        #pragma unroll
        for (int r = 0; r < 4; r++) {
            int o = oA + mt * 16 + quad * 4 + r;
            float ba = glu_b[li * 512 + o];
            float bg = glu_b[li * 512 + 256 + o];
            const ushort_t* hrow = hb_ + (size_t)o * 4096 + l0 + ln15;
            #pragma unroll
            for (int nt = 0; nt < 4; nt++) {
                float a = accA[mt][nt][r] + ba;
                float g = accG[mt][nt][r] + bg;
                float z = a / (1.f + expf(-g));
                float hn = z + bf2f(hrow[nt * 16]);
                accA[mt][nt][r] = hn;
                ps[nt] += hn; pq[nt] = fmaf(hn, hn, pq[nt]);
            }
        }
    }
    int slot = w * 4 + quad;
    #pragma unroll
    for (int nt = 0; nt < 4; nt++) {
        redS[slot][nt * 16 + ln15] = ps[nt];
        redQ[slot][nt * 16 + ln15] = pq[nt];
    }
    __syncthreads();
    if (t < 64) {
        float S = 0.f, Q = 0.f;
        #pragma unroll
        for (int s_ = 0; s_ < 16; s_++) { S += redS[s_][t]; Q += redQ[s_][t]; }
        float mu = S * (1.f / 256.f);
        float var = Q * (1.f / 256.f) - mu * mu;
        mup[t] = mu; rstd[t] = rsqrtf(var + 1e-5f);
    }
    __syncthreads();
    #pragma unroll
    for (int mt = 0; mt < 4; mt++) {
        #pragma unroll
        for (int r = 0; r < 4; r++) {
            int o = oA + mt * 16 + quad * 4 + r;
            float gm = ln_g[li * 256 + o];
            float bt = ln_b[li * 256 + o];
            ushort_t* hrow = hb_ + (size_t)o * 4096 + l0 + ln15;
            #pragma unroll
            for (int nt = 0; nt < 4; nt++) {
                int p = nt * 16 + ln15;
                float v = (accA[mt][nt][r] - mup[p]) * rstd[p] * gm + bt;
                hrow[nt * 16] = f2bf(v);
            }
        }
    }
}

// ---------------- decoder (bf16 h) ----------------
__global__ __launch_bounds__(256) void dec1_kernel(const ushort_t* __restrict__ Hb,
    const float* __restrict__ w1, const float* __restrict__ b1, float* __restrict__ y1)
{
    int bh = blockIdx.x;
    const ushort_t* base = Hb + (size_t)bh * 4096;
    int t = threadIdx.x;
    float s = 0.f;
    for (int l = t; l < 4096; l += 256) s = fmaf(bf2f(base[l]), w1[l], s);
    #pragma unroll
    for (int d = 32; d > 0; d >>= 1) s += __shfl_xor(s, d, 64);
    __shared__ float red[4];
    if ((t & 63) == 0) red[t >> 6] = s;
    __syncthreads();
    if (t == 0) y1[bh] = red[0] + red[1] + red[2] + red[3] + b1[0];
}

__global__ __launch_bounds__(256) void dec2_kernel(const float* __restrict__ y1,
    const float* __restrict__ w2, const float* __restrict__ b2, float* __restrict__ out)
{
    int t = threadIdx.x;
    int b = blockIdx.x * 4 + (t >> 6);
    int lane = t & 63;
    float s = 0.f;
    #pragma unroll
    for (int k = 0; k < 4; k++) s = fmaf(y1[b * 256 + lane + k * 64], w2[lane + k * 64], s);
    #pragma unroll
    for (int d = 32; d > 0; d >>= 1) s += __shfl_xor(s, d, 64);
    if (lane == 0) out[b] = 1.f / (1.f + expf(-(s + b2[0])));
}

extern "C" void kernel_launch(void* const* d_in, const int* in_sizes, int n_in,
                              void* d_out, int out_size, void* d_ws, size_t ws_size,
                              hipStream_t stream)
{
    const float* x      = (const float*)d_in[0];
    const float* enc_w  = (const float*)d_in[1];
    const float* enc_b  = (const float*)d_in[2];
    const float* log_dt = (const float*)d_in[3];
    const float* lAr    = (const float*)d_in[4];
    const float* Aim    = (const float*)d_in[5];
    const float* Cre    = (const float*)d_in[6];
    const float* Cim    = (const float*)d_in[7];
    const float* Dp     = (const float*)d_in[8];
    const float* glu_w  = (const float*)d_in[9];
    const float* glu_b  = (const float*)d_in[10];
    const float* ln_g   = (const float*)d_in[11];
    const float* ln_b   = (const float*)d_in[12];
    const float* w1     = (const float*)d_in[13];
    const float* b1     = (const float*)d_in[14];
    const float* w2     = (const float*)d_in[15];
    const float* b2     = (const float*)d_in[16];

    float* ws = (float*)d_ws;
    ushort_t* Hb   = (ushort_t*)ws;
    ushort_t* wTb  = (ushort_t*)(ws + WS_WT);
    float* y1      = ws + WS_Y1;
    float* a256    = ws + WS_A256;
    ushort_t* Vg   = (ushort_t*)(ws + WS_V);
    ushort_t* Abuf = (ushort_t*)(ws + WS_ABUF);
    float* outp    = (float*)d_out;

    size_t wsf = ws_size / 4;
    int nb = 32;
    while (nb > 4 && (size_t)WS_S + (size_t)nb * 655360 > wsf) nb >>= 1;
    int ntot = nb * 16;
    ushort_t* Sb = (ushort_t*)(ws + WS_S);
    ushort_t* Gb = (ushort_t*)(ws + WS_S + (size_t)nb * 131072);

    wtb_kernel<<<2048, 256, 0, stream>>>(glu_w, wTb);
    enc_kernel<<<16384, 256, 0, stream>>>(x, enc_w, enc_b, Hb);
    for (int li = 0; li < 4; li++) {
        prep_kernel<<<256, 256, 0, stream>>>(log_dt, lAr, Aim, Cre, Cim, Abuf, Vg, a256, li);
        for (int b0 = 0; b0 < 32; b0 += nb) {
            vgemm_kernel<<<dim3(256, nb / 4), 256, 0, stream>>>(Hb, Vg, Sb, b0, ntot);
            scan_kernel<<<nb * 32, 256, 0, stream>>>(Sb, a256, ntot);
            dgemm_kernel<<<dim3(256, nb / 4), 256, 0, stream>>>(Hb, Abuf, Sb, Dp, Gb, li, b0, ntot);
            gluln_kernel<<<nb * 64, 256, 0, stream>>>(Gb, wTb, glu_b, ln_g, ln_b, Hb, li, b0);
        }
    }
    dec1_kernel<<<8192, 256, 0, stream>>>(Hb, w1, b1, y1);
    dec2_kernel<<<8, 256, 0, stream>>>(y1, w2, b2, outp);
}